// Round 11
// baseline (2758.138 us; speedup 1.0000x reference)
//
#include <hip/hip_runtime.h>
#include <stdint.h>

#define B_   2
#define S_   2048
#define D_   1024
#define DA_  512
#define DFF_ 2048
#define V_   32000
#define L_   12
#define M_   (B_ * S_)  // 4096

typedef __attribute__((ext_vector_type(4))) float f32x4;
typedef __attribute__((ext_vector_type(8))) short short8;
typedef __attribute__((ext_vector_type(4))) short short4v;

__device__ __forceinline__ short f2bf(float f) {
  uint32_t u = __float_as_uint(f);
  u += 0x7fffu + ((u >> 16) & 1u);
  return (short)(u >> 16);
}

__device__ __forceinline__ void gload16(const short* g, short* l) {
  __builtin_amdgcn_global_load_lds(
      (const __attribute__((address_space(1))) char*)g,
      (__attribute__((address_space(3))) char*)l, 16, 0, 0);
}

// ---------------------------------------------------------------------------
// 256x256 8-phase bf16 GEMM (T2 swizzle + T3/T4 counted vmcnt + T5 setprio).
// ---------------------------------------------------------------------------
__global__ __launch_bounds__(512, 2) void gemm8p(
    const short* __restrict__ A, int lda,
    const short* __restrict__ Bt, int ldb,
    float* __restrict__ C, int ldc,
    const float* __restrict__ bias, int K) {
  __shared__ __align__(16) short lds[2][2][256 * 64];  // [buf][A=0/B=1][row*64+c]
  const int t = threadIdx.x;
  const int lane = t & 63, wid = t >> 6;
  const int wm = wid >> 2, wn = wid & 3;
  const int l15 = lane & 15, l4 = lane >> 4;
  const int brow = blockIdx.x * 256, bcol = blockIdx.y * 256;
  const short* Ab = A + (long long)brow * lda;
  const short* Bb = Bt + (long long)bcol * ldb;

  const int rr = t >> 3;                      // row within 64-row issue block
  const int gcol = ((t & 7) ^ (rr & 7)) * 8;  // swizzled source col (elements)
  const int ldsoff = wid * 512;               // shorts: wid*8 rows * 64

  const int ord_m[8] = {0, 0, 1, 1, 1, 1, 0, 0};
  const int ord_r[8] = {0, 128, 0, 64, 128, 192, 64, 192};

#define STAGE8(mat, row0, buf, ko)                                            \
  gload16(((mat) ? Bb : Ab) +                                                 \
              (long long)((row0) + rr) * ((mat) ? ldb : lda) + (ko) + gcol,   \
          &lds[buf][mat][(row0) * 64 + ldsoff])

  f32x4 acc[8][4] = {};
  const int nkt = K >> 6;  // assumed EVEN (epilogue LDS-reuse relies on it)

  // prologue: stage tile 0 into buf 0
#pragma unroll
  for (int j = 0; j < 8; ++j) STAGE8(ord_m[j], ord_r[j], 0, 0);
  asm volatile("s_waitcnt vmcnt(2)" ::: "memory");
  __builtin_amdgcn_s_barrier();

  for (int kt = 0; kt < nkt; ++kt) {
    const int buf = kt & 1, nbuf = buf ^ 1;
    const int kon = (kt + 1 < nkt ? (kt + 1) : kt) << 6;  // clamp: uniform counts
    short8 bfr[4][2];
#pragma unroll
    for (int p = 0; p < 4; ++p) {
      short8 af[2][2];
      const int arow = wm * 128 + p * 32;
#pragma unroll
      for (int mf = 0; mf < 2; ++mf)
#pragma unroll
        for (int ks = 0; ks < 2; ++ks) {
          const int row = arow + mf * 16 + l15;
          const int cs = (ks * 32 + l4 * 8) ^ ((row & 7) << 3);
          af[mf][ks] = *(const short8*)&lds[buf][0][row * 64 + cs];
        }
      if (p == 0) {
#pragma unroll
        for (int nf = 0; nf < 4; ++nf)
#pragma unroll
          for (int ks = 0; ks < 2; ++ks) {
            const int row = wn * 64 + nf * 16 + l15;
            const int cs = (ks * 32 + l4 * 8) ^ ((row & 7) << 3);
            bfr[nf][ks] = *(const short8*)&lds[buf][1][row * 64 + cs];
          }
      }
      STAGE8(ord_m[2 * p], ord_r[2 * p], nbuf, kon);
      STAGE8(ord_m[2 * p + 1], ord_r[2 * p + 1], nbuf, kon);
      __builtin_amdgcn_s_barrier();
      asm volatile("s_waitcnt lgkmcnt(0)" ::: "memory");
      __builtin_amdgcn_sched_barrier(0);
      __builtin_amdgcn_s_setprio(1);
#pragma unroll
      for (int mf = 0; mf < 2; ++mf)
#pragma unroll
        for (int nf = 0; nf < 4; ++nf) {
          acc[p * 2 + mf][nf] = __builtin_amdgcn_mfma_f32_16x16x32_bf16(
              af[mf][0], bfr[nf][0], acc[p * 2 + mf][nf], 0, 0, 0);
          acc[p * 2 + mf][nf] = __builtin_amdgcn_mfma_f32_16x16x32_bf16(
              af[mf][1], bfr[nf][1], acc[p * 2 + mf][nf], 0, 0, 0);
        }
      __builtin_amdgcn_s_setprio(0);
      if (p == 1) asm volatile("s_waitcnt vmcnt(4)" ::: "memory");
      if (p == 3) asm volatile("s_waitcnt vmcnt(2)" ::: "memory");
      __builtin_amdgcn_s_barrier();
    }
  }

  // epilogue: acc -> per-wave LDS (stride-68 f32) -> 256-B nt f32x4 stores
  {
    float* ep = (float*)&lds[1][0][0] + wid * 1088;  // 4352 B per wave
    float bb[4];
#pragma unroll
    for (int nf = 0; nf < 4; ++nf) bb[nf] = bias[bcol + wn * 64 + nf * 16 + l15];
#pragma unroll
    for (int mi = 0; mi < 8; ++mi) {
#pragma unroll
      for (int nf = 0; nf < 4; ++nf) {
        const f32x4 v = acc[mi][nf];
#pragma unroll
        for (int j = 0; j < 4; ++j)
          ep[(l4 * 4 + j) * 68 + nf * 16 + l15] = v[j] + bb[nf];
      }
#pragma unroll
      for (int i = 0; i < 4; ++i) {
        const f32x4 v = *(const f32x4*)&ep[(l4 + 4 * i) * 68 + l15 * 4];
        const int row_g = brow + wm * 128 + mi * 16 + l4 + 4 * i;
        const int col_g = bcol + wn * 64 + l15 * 4;
        __builtin_nontemporal_store(v, (f32x4*)&C[(long long)row_g * ldc + col_g]);
      }
    }
  }
#undef STAGE8
}

// ---------------------------------------------------------------------------
// 256x128-tile, 2-PHASE-per-K-tile variant (16 MFMA/phase). TRV: V slice of
// QKV written transposed into Vt via per-wave LDS staging.
// ---------------------------------------------------------------------------
template <bool RELU, bool TRV>
__global__ __launch_bounds__(512, 2) void gemm8pA2(
    const short* __restrict__ A, int lda,
    const short* __restrict__ Bt, int ldb,
    short* __restrict__ C, int ldc,
    short* __restrict__ Vt,
    const float* __restrict__ bias, int K) {
  __shared__ __align__(16) short ldsA[2][256 * 64];  // 64 KB
  __shared__ __align__(16) short ldsB[2][128 * 64];  // 32 KB
  const int t = threadIdx.x;
  const int lane = t & 63, wid = t >> 6;
  const int wm = wid >> 2, wn = wid & 3;
  const int l15 = lane & 15, l4 = lane >> 4;
  const int brow = blockIdx.x * 256, bcol = blockIdx.y * 128;
  const short* Ab = A + (long long)brow * lda;
  const short* Bb = Bt + (long long)bcol * ldb;

  const int rr = t >> 3;
  const int gcol = ((t & 7) ^ (rr & 7)) * 8;
  const int ldsoff = wid * 512;

#define SA(row0, buf, ko) \
  gload16(Ab + (long long)((row0) + rr) * lda + (ko) + gcol, &ldsA[buf][(row0) * 64 + ldsoff])
#define SB(row0, buf, ko) \
  gload16(Bb + (long long)((row0) + rr) * ldb + (ko) + gcol, &ldsB[buf][(row0) * 64 + ldsoff])

  f32x4 acc[8][2] = {};
  const int nkt = K >> 6;

  // prologue: tile 0 -> buf 0
  SA(0, 0, 0);
  SA(128, 0, 0);
  SB(0, 0, 0);
  SB(64, 0, 0);
  SA(64, 0, 0);
  SA(192, 0, 0);
  asm volatile("s_waitcnt vmcnt(2)" ::: "memory");
  __builtin_amdgcn_s_barrier();

  for (int kt = 0; kt < nkt; ++kt) {
    const int buf = kt & 1, nbuf = buf ^ 1;
    const int kon = (kt + 1 < nkt ? (kt + 1) : kt) << 6;  // clamp: uniform counts
    short8 bfr[2][2];
#pragma unroll
    for (int q = 0; q < 2; ++q) {
      short8 af[4][2];
      const int arow = wm * 128 + q * 64;
#pragma unroll
      for (int mf = 0; mf < 4; ++mf)
#pragma unroll
        for (int ks = 0; ks < 2; ++ks) {
          const int row = arow + mf * 16 + l15;
          const int cs = (ks * 32 + l4 * 8) ^ ((row & 7) << 3);
          af[mf][ks] = *(const short8*)&ldsA[buf][row * 64 + cs];
        }
      if (q == 0) {
#pragma unroll
        for (int nf = 0; nf < 2; ++nf)
#pragma unroll
          for (int ks = 0; ks < 2; ++ks) {
            const int row = wn * 32 + nf * 16 + l15;
            const int cs = (ks * 32 + l4 * 8) ^ ((row & 7) << 3);
            bfr[nf][ks] = *(const short8*)&ldsB[buf][row * 64 + cs];
          }
        SA(0, nbuf, kon);
        SA(128, nbuf, kon);
        SB(0, nbuf, kon);
      } else {
        SB(64, nbuf, kon);
        SA(64, nbuf, kon);
        SA(192, nbuf, kon);
      }
      __builtin_amdgcn_s_barrier();
      asm volatile("s_waitcnt lgkmcnt(0)" ::: "memory");
      __builtin_amdgcn_sched_barrier(0);
      __builtin_amdgcn_s_setprio(1);
#pragma unroll
      for (int mf = 0; mf < 4; ++mf)
#pragma unroll
        for (int nf = 0; nf < 2; ++nf) {
          acc[q * 4 + mf][nf] = __builtin_amdgcn_mfma_f32_16x16x32_bf16(
              af[mf][0], bfr[nf][0], acc[q * 4 + mf][nf], 0, 0, 0);
          acc[q * 4 + mf][nf] = __builtin_amdgcn_mfma_f32_16x16x32_bf16(
              af[mf][1], bfr[nf][1], acc[q * 4 + mf][nf], 0, 0, 0);
        }
      __builtin_amdgcn_s_setprio(0);
      if (q == 0) asm volatile("s_waitcnt vmcnt(3)" ::: "memory");
      else        asm volatile("s_waitcnt vmcnt(2)" ::: "memory");
      __builtin_amdgcn_s_barrier();
    }
  }

  if (TRV && bcol >= 1024) {
    // transposed epilogue -> Vt[vcol][M]
    __shared__ __align__(16) short eplds[8][2176];  // 16 cols x 136 stride
    short* ep = eplds[wid];
    const int vc0 = bcol - 1024 + wn * 32;
#pragma unroll
    for (int nf = 0; nf < 2; ++nf) {
      const float bb = bias[bcol + wn * 32 + nf * 16 + l15];
#pragma unroll
      for (int mi = 0; mi < 8; ++mi) {
        short4v pk;
#pragma unroll
        for (int j = 0; j < 4; ++j) pk[j] = f2bf(acc[mi][nf][j] + bb);
        *(short4v*)&ep[l15 * 136 + mi * 16 + l4 * 4] = pk;
      }
#pragma unroll
      for (int rd = 0; rd < 4; ++rd) {
        const int cl = rd * 4 + (lane >> 4);  // col-local 0..15
        const int rc = (lane & 15) * 8;       // row chunk
        const short8 v = *(const short8*)&ep[cl * 136 + rc];
        *(short8*)(Vt + (long long)(vc0 + nf * 16 + cl) * M_ + brow + wm * 128 + rc) = v;
      }
    }
  } else {
    // row-major bf16 epilogue
#pragma unroll
    for (int nf = 0; nf < 2; ++nf) {
      const int col = bcol + wn * 32 + nf * 16 + l15;
      const float bb = bias[col];
#pragma unroll
      for (int mi = 0; mi < 8; ++mi) {
        const int row0 = brow + wm * 128 + mi * 16 + l4 * 4;
        f32x4 v = acc[mi][nf];
#pragma unroll
        for (int j = 0; j < 4; ++j) {
          float z = v[j] + bb;
          if (RELU) z = fmaxf(z, 0.0f);
          C[(long long)(row0 + j) * ldc + col] = f2bf(z);
        }
      }
    }
  }
#undef SA
#undef SB
}

// ---------------------------------------------------------------------------
// bf16 MFMA GEMM: C[M,N] = act(A[M,K] @ Bt[N,K]^T + bias)
// Tile: 128 x BN, BK=128 (4 ks-steps per barrier pair -> half the drain
// overhead of BK=64; same k accumulation order -> bit-identical output).
// LDS 48 KB at BN=64 (3 blocks/CU capacity; grids need <=2). FLIP: reverse
// bm for z==1 so co-resident causal blocks get complementary K-depths.
// OUT_MODE 0 stores are nontemporal (sc/att32 are write-once streams).
// ---------------------------------------------------------------------------
template <int BN, int OUT_MODE, bool RELU, int CAUSAL, int BIAS_MODE, bool FLIP>
__global__ __launch_bounds__(256) void gemm_bt(
    const short* __restrict__ A, int lda, long long batchA,
    const short* __restrict__ Bt, int ldb, long long batchB,
    void* __restrict__ Cp, int ldc, long long batchC,
    void* __restrict__ Cp2, const float* __restrict__ bias, int M, int N, int K) {
  const int bz = blockIdx.z;
  const int bm = (FLIP && bz == 1) ? (gridDim.x - 1 - blockIdx.x) : blockIdx.x;
  const int bn = blockIdx.y;
  if (CAUSAL == 1 && bn * BN >= bm * 128 + 128) return;
  const int brow = bm * 128, bcol = bn * BN;
  const short* Ab = A + (long long)bz * batchA;
  const short* Bb = Bt + (long long)bz * batchB;

  const int kend = (CAUSAL == 2) ? min(K, brow + 128) : K;  // multiple of 128

  __shared__ __align__(16) short As[128 * 128];
  __shared__ __align__(16) short Bs[BN * 128];

  const int t = threadIdx.x;
  const int lane = t & 63, wid = t >> 6;
  constexpr int M_REP = (BN == 128) ? 4 : 2;
  const int wr = (BN == 128) ? (wid >> 1) : wid;
  const int wc = (BN == 128) ? (wid & 1) : 0;
  const int rbase = wr * (M_REP * 16);
  const int cbase = wc * 64;
  const int l15 = lane & 15, l4 = lane >> 4;

  f32x4 acc[M_REP][4] = {};

  for (int ko = 0; ko < kend; ko += 128) {
    // stage A (128x128 = 8 iters) and B (BNx128) ; row = c>>4, chunk = c&15
#pragma unroll
    for (int i = 0; i < 8; i++) {
      const int c = t + i * 256;
      gload16(Ab + (long long)(brow + (c >> 4)) * lda + ko + ((c & 15) << 3),
              As + (i * 256 + wid * 64) * 8);
    }
#pragma unroll
    for (int i = 0; i < BN / 16; i++) {
      const int c = t + i * 256;
      gload16(Bb + (long long)(bcol + (c >> 4)) * ldb + ko + ((c & 15) << 3),
              Bs + (i * 256 + wid * 64) * 8);
    }
    __syncthreads();  // drains vmcnt -> staged data visible
#pragma unroll
    for (int ks = 0; ks < 4; ks++) {
      short8 af[M_REP], bfr[4];
#pragma unroll
      for (int m = 0; m < M_REP; m++)
        af[m] = *(const short8*)(As + (rbase + m * 16 + l15) * 128 + ks * 32 + l4 * 8);
#pragma unroll
      for (int n = 0; n < 4; n++)
        bfr[n] = *(const short8*)(Bs + (cbase + n * 16 + l15) * 128 + ks * 32 + l4 * 8);
#pragma unroll
      for (int m = 0; m < M_REP; m++)
#pragma unroll
        for (int n = 0; n < 4; n++)
          acc[m][n] = __builtin_amdgcn_mfma_f32_16x16x32_bf16(af[m], bfr[n], acc[m][n], 0, 0, 0);
    }
    __syncthreads();  // all waves done reading before next overwrite
  }

  // epilogue: C/D layout col = lane&15, row = (lane>>4)*4 + reg  [m89-verified]
#pragma unroll
  for (int n = 0; n < 4; n++) {
    const int col = bcol + cbase + n * 16 + l15;
    const float bcv = (BIAS_MODE == 0 && bias) ? bias[col] : 0.0f;
#pragma unroll
    for (int m = 0; m < M_REP; m++) {
      const int row0 = brow + rbase + m * 16 + l4 * 4;
      f32x4 v = acc[m][n];
#pragma unroll
      for (int j = 0; j < 4; j++) {
        const float bb = (BIAS_MODE == 0) ? bcv : (bias ? bias[row0 + j] : 0.0f);
        float z = v[j] + bb;
        if (RELU) z = fmaxf(z, 0.0f);
        v[j] = z;
      }
      if (OUT_MODE == 0) {
        float* C = (float*)Cp + (long long)bz * batchC;
#pragma unroll
        for (int j = 0; j < 4; j++)
          __builtin_nontemporal_store(v[j], &C[(long long)(row0 + j) * ldc + col]);
      } else if (OUT_MODE == 1) {
        short* C = (short*)Cp + (long long)bz * batchC;
#pragma unroll
        for (int j = 0; j < 4; j++) C[(long long)(row0 + j) * ldc + col] = f2bf(v[j]);
      } else {  // 3: dual f32 + bf16
        float* C = (float*)Cp;
        short* C2 = (short*)Cp2;
#pragma unroll
        for (int j = 0; j < 4; j++) {
          C[(long long)(row0 + j) * ldc + col] = v[j];
          C2[(long long)(row0 + j) * ldc + col] = f2bf(v[j]);
        }
      }
    }
  }
}

// ---------------------------------------------------------------------------
// Weight prep: f32 [Z][R][C] (z-stride in_zs) -> bf16 [Z][C][R] (z-stride out_zs)
// ---------------------------------------------------------------------------
__global__ void transpose_convert(const float* __restrict__ in, short* __restrict__ out,
                                  int R, int C, long long in_zs, long long out_zs) {
  __shared__ float tile[32][33];
  in += (long long)blockIdx.z * in_zs;
  out += (long long)blockIdx.z * out_zs;
  const int c0 = blockIdx.x * 32, r0 = blockIdx.y * 32;
  const int tx = threadIdx.x, ty = threadIdx.y;
#pragma unroll
  for (int i = 0; i < 32; i += 8)
    tile[ty + i][tx] = in[(long long)(r0 + ty + i) * C + (c0 + tx)];
  __syncthreads();
#pragma unroll
  for (int i = 0; i < 32; i += 8)
    out[(long long)(c0 + ty + i) * R + (r0 + tx)] = f2bf(tile[tx][ty + i]);
}

__global__ void concat_bias3(const float* __restrict__ bq, const float* __restrict__ bk,
                             const float* __restrict__ bv, float* __restrict__ dst) {
  const int l = blockIdx.x, t = threadIdx.x;  // 1024 threads
  if (t < 512) {
    dst[(long long)l * 2048 + t] = bq[(long long)l * 512 + t];
    dst[(long long)l * 2048 + 512 + t] = bk[(long long)l * 512 + t];
  }
  dst[(long long)l * 2048 + 1024 + t] = bv[(long long)l * 1024 + t];
}

__global__ void embed_kernel(const int* __restrict__ x, const float* __restrict__ emb,
                             float* __restrict__ h32, short* __restrict__ h16) {
  const int m = blockIdx.x, t = threadIdx.x;
  const int tok = x[m];
  f32x4 v = ((const f32x4*)(emb + (long long)tok * D_))[t];
  ((f32x4*)(h32 + (long long)m * D_))[t] = v;
  short4v s;
#pragma unroll
  for (int j = 0; j < 4; j++) s[j] = f2bf(v[j]);
  ((short4v*)(h16 + (long long)m * D_))[t] = s;
}

// LDS-staged causal softmax: 1 global read of the row, exp cached in LDS.
__global__ __launch_bounds__(256) void softmax_kernel(const float* __restrict__ scores,
                                                      short* __restrict__ P) {
  __shared__ float row[S_];  // 8 KB
  __shared__ float red[8];
  const int r = blockIdx.x, b = blockIdx.y;
  const float* srow = scores + ((long long)b * S_ + r) * S_;
  short* prow = P + ((long long)b * S_ + r) * S_;
  const int t = threadIdx.x;
  const int n = r + 1;                          // valid columns
  const int nw = min(S_, ((r >> 7) + 1) << 7);  // 128-aligned write extent
  for (int c = t * 4; c < nw; c += 1024)
    *(f32x4*)(row + c) = *(const f32x4*)(srow + c);
  __syncthreads();
  float mx = -3.4e38f;
  for (int c = t; c < n; c += 256) mx = fmaxf(mx, row[c]);
  for (int off = 32; off; off >>= 1) mx = fmaxf(mx, __shfl_down(mx, off));
  const int lane = t & 63, wid = t >> 6;
  if (lane == 0) red[wid] = mx;
  __syncthreads();
  mx = fmaxf(fmaxf(red[0], red[1]), fmaxf(red[2], red[3]));
  float sum = 0.f;
  for (int c = t; c < n; c += 256) {
    const float e = __expf(row[c] - mx);
    row[c] = e;
    sum += e;
  }
  for (int off = 32; off; off >>= 1) sum += __shfl_down(sum, off);
  __syncthreads();  // red[] reuse
  if (lane == 0) red[4 + wid] = sum;
  __syncthreads();
  sum = red[4] + red[5] + red[6] + red[7];
  const float inv = 1.0f / sum;
  for (int c = t; c < nw; c += 256)
    prow[c] = f2bf((c < n) ? row[c] * inv : 0.0f);
}

__global__ __launch_bounds__(256) void ln_kernel(float* __restrict__ h32, short* __restrict__ h16,
                                                 const float* __restrict__ att,
                                                 const float* __restrict__ g,
                                                 const float* __restrict__ bb) {
  const int m = blockIdx.x, t = threadIdx.x;
  f32x4 hv = ((const f32x4*)(h32 + (long long)m * D_))[t];
  f32x4 av = ((const f32x4*)(att + (long long)m * D_))[t];
  float y[4];
  float s = 0.f, ss = 0.f;
#pragma unroll
  for (int j = 0; j < 4; j++) {
    y[j] = hv[j] + av[j];
    s += y[j];
    ss += y[j] * y[j];
  }
  for (int off = 32; off; off >>= 1) {
    s += __shfl_down(s, off);
    ss += __shfl_down(ss, off);
  }
  __shared__ float red[8];
  const int lane = t & 63, wid = t >> 6;
  if (lane == 0) {
    red[wid] = s;
    red[4 + wid] = ss;
  }
  __syncthreads();
  s = red[0] + red[1] + red[2] + red[3];
  ss = red[4] + red[5] + red[6] + red[7];
  const float mu = s * (1.0f / D_);
  const float var = ss * (1.0f / D_) - mu * mu;
  const float inv = rsqrtf(var + 1e-5f);
  f32x4 gv = ((const f32x4*)g)[t];
  f32x4 bv = ((const f32x4*)bb)[t];
  f32x4 o;
  short4v ob;
#pragma unroll
  for (int j = 0; j < 4; j++) {
    const float z = (y[j] - mu) * inv * gv[j] + bv[j];
    o[j] = z;
    ob[j] = f2bf(z);
  }
  ((f32x4*)(h32 + (long long)m * D_))[t] = o;
  ((short4v*)(h16 + (long long)m * D_))[t] = ob;
}

// ---------------------------------------------------------------------------
extern "C" void kernel_launch(void* const* d_in, const int* in_sizes, int n_in,
                              void* d_out, int out_size, void* d_ws, size_t ws_size,
                              hipStream_t stream) {
  const int* x = (const int*)d_in[0];
  const float* emb = (const float*)d_in[1];
  const float* Wq = (const float*)d_in[2];
  const float* bq = (const float*)d_in[3];
  const float* Wk = (const float*)d_in[4];
  const float* bk = (const float*)d_in[5];
  const float* Wv = (const float*)d_in[6];
  const float* bv = (const float*)d_in[7];
  const float* ln_g = (const float*)d_in[8];
  const float* ln_b = (const float*)d_in[9];
  const float* W1 = (const float*)d_in[10];
  const float* b1 = (const float*)d_in[11];
  const float* W2 = (const float*)d_in[12];
  const float* b2 = (const float*)d_in[13];
  const float* Wout = (const float*)d_in[14];
  const float* bout = (const float*)d_in[15];
  float* out = (float*)d_out;

  char* p = (char*)d_ws;
  auto alloc = [&](long long bytes) -> char* {
    char* r = p;
    p += (bytes + 255) & ~255LL;
    return r;
  };
  // wqkv packed [L][2048 rows (q:0-511, k:512-1023, v:1024-2047)][D]
  short* wqkv_t = (short*)alloc((long long)L_ * 2048 * D_ * 2);
  short* w1_t = (short*)alloc((long long)L_ * DFF_ * D_ * 2);
  short* w2_t = (short*)alloc((long long)L_ * D_ * DFF_ * 2);
  short* wout_t = (short*)alloc((long long)V_ * D_ * 2);
  float* bqkv = (float*)alloc((long long)L_ * 2048 * 4);
  short* h16 = (short*)alloc((long long)M_ * D_ * 2);
  float* h32 = (float*)alloc((long long)M_ * D_ * 4);
  short* qkv = (short*)alloc((long long)M_ * 2048 * 2);  // [4096][2048] q|k|(v unused)
  short* vt = (short*)alloc((long long)D_ * M_ * 2);     // [1024][4096]
  float* sc = (float*)alloc((long long)B_ * S_ * S_ * 4);
  short* Pm = (short*)alloc((long long)B_ * S_ * S_ * 2);
  float* att32 = (float*)alloc((long long)M_ * D_ * 4);
  short* mid = (short*)alloc((long long)M_ * DFF_ * 2);

  const dim3 tb(32, 8);
  const long long qkv_zs = (long long)2048 * D_;
  transpose_convert<<<dim3(DA_ / 32, D_ / 32, L_), tb, 0, stream>>>(
      Wq, wqkv_t, D_, DA_, (long long)D_ * DA_, qkv_zs);
  transpose_convert<<<dim3(DA_ / 32, D_ / 32, L_), tb, 0, stream>>>(
      Wk, wqkv_t + (long long)DA_ * D_, D_, DA_, (long long)D_ * DA_, qkv_zs);
  transpose_convert<<<dim3(D_ / 32, D_ / 32, L_), tb, 0, stream>>>(
      Wv, wqkv_t + (long long)D_ * D_, D_, D_, (long long)D_ * D_, qkv_zs);
  transpose_convert<<<dim3(DFF_ / 32, D_ / 32, L_), tb, 0, stream>>>(
      W1, w1_t, D_, DFF_, (long long)D_ * DFF_, (long long)D_ * DFF_);
  transpose_convert<<<dim3(D_ / 32, DFF_ / 32, L_), tb, 0, stream>>>(
      W2, w2_t, DFF_, D_, (long long)DFF_ * D_, (long long)DFF_ * D_);
  transpose_convert<<<dim3(V_ / 32, D_ / 32, 1), tb, 0, stream>>>(
      Wout, wout_t, D_, V_, (long long)D_ * V_, (long long)D_ * V_);
  concat_bias3<<<L_, 1024, 0, stream>>>(bq, bk, bv, bqkv);

  embed_kernel<<<M_, 256, 0, stream>>>(x, emb, h32, h16);

  for (int i = 0; i < L_; i++) {
    const short* wqkv_l = wqkv_t + (long long)i * qkv_zs;
    const short* w1_l = w1_t + (long long)i * DFF_ * D_;
    const short* w2_l = w2_t + (long long)i * D_ * DFF_;

    // QKV (8-phase 2ph/K-tile, 256 blocks); V slice written transposed -> vt
    gemm8pA2<false, true><<<dim3(M_ / 256, 2048 / 128), 512, 0, stream>>>(
        h16, D_, wqkv_l, D_, qkv, 2048, vt, bqkv + (long long)i * 2048, D_);
    // scores[b] = Q[b] @ K[b]^T  f32, causal tile-skip, z-flip balanced, BK=128
    gemm_bt<64, 0, false, 1, 0, true><<<dim3(S_ / 128, S_ / 64, B_), 256, 0, stream>>>(
        qkv, 2048, (long long)S_ * 2048, qkv + DA_, 2048, (long long)S_ * 2048,
        sc, S_, (long long)S_ * S_, nullptr, nullptr, S_, S_, DA_);
    // causal softmax -> P bf16 (zeros up to diagonal tile edge)
    softmax_kernel<<<dim3(S_, B_), 256, 0, stream>>>(sc, Pm);
    // att[b] = P[b] @ V[b]  f32, k-loop clipped, z-flip balanced, BK=128
    gemm_bt<64, 0, false, 2, 0, true><<<dim3(S_ / 128, D_ / 64, B_), 256, 0, stream>>>(
        Pm, S_, (long long)S_ * S_, vt, M_, (long long)S_, att32, D_,
        (long long)S_ * D_, nullptr, nullptr, S_, D_, S_);
    // h = LN(h + att)  (f32 master + bf16 shadow)
    ln_kernel<<<M_, 256, 0, stream>>>(h32, h16, att32, ln_g + (long long)i * D_,
                                      ln_b + (long long)i * D_);
    // mid = relu(h @ W1 + b1)  bf16  (8-phase 2ph/K-tile, 256 blocks)
    gemm8pA2<true, false><<<dim3(M_ / 256, DFF_ / 128), 512, 0, stream>>>(
        h16, D_, w1_l, D_, mid, DFF_, nullptr, b1 + (long long)i * DFF_, D_);
    // h = mid @ W2 + b2 -> f32 master + bf16 shadow  (BK=128, 512 blocks)
    gemm_bt<64, 3, false, 0, 0, false><<<dim3(M_ / 128, D_ / 64, 1), 256, 0, stream>>>(
        mid, DFF_, 0, w2_l, DFF_, 0, h32, D_, 0, h16,
        b2 + (long long)i * D_, M_, D_, DFF_);
  }

  // logits = h @ Wout + bout  f32 -> d_out  (256^2 8-phase, 2000 blocks)
  gemm8p<<<dim3(M_ / 256, V_ / 256), 512, 0, stream>>>(
      h16, D_, wout_t, D_, out, V_, bout, D_);
}

// Round 12
// 2531.776 us; speedup vs baseline: 1.0894x; 1.0894x over previous
//
#include <hip/hip_runtime.h>
#include <stdint.h>

#define B_   2
#define S_   2048
#define D_   1024
#define DA_  512
#define DFF_ 2048
#define V_   32000
#define L_   12
#define M_   (B_ * S_)  // 4096

typedef __attribute__((ext_vector_type(4))) float f32x4;
typedef __attribute__((ext_vector_type(8))) short short8;
typedef __attribute__((ext_vector_type(4))) short short4v;

__device__ __forceinline__ short f2bf(float f) {
  uint32_t u = __float_as_uint(f);
  u += 0x7fffu + ((u >> 16) & 1u);
  return (short)(u >> 16);
}

__device__ __forceinline__ void gload16(const short* g, short* l) {
  __builtin_amdgcn_global_load_lds(
      (const __attribute__((address_space(1))) char*)g,
      (__attribute__((address_space(3))) char*)l, 16, 0, 0);
}

// ---------------------------------------------------------------------------
// 256x256 8-phase bf16 GEMM (T2 swizzle + T3/T4 counted vmcnt + T5 setprio).
// ---------------------------------------------------------------------------
__global__ __launch_bounds__(512, 2) void gemm8p(
    const short* __restrict__ A, int lda,
    const short* __restrict__ Bt, int ldb,
    float* __restrict__ C, int ldc,
    const float* __restrict__ bias, int K) {
  __shared__ __align__(16) short lds[2][2][256 * 64];  // [buf][A=0/B=1][row*64+c]
  const int t = threadIdx.x;
  const int lane = t & 63, wid = t >> 6;
  const int wm = wid >> 2, wn = wid & 3;
  const int l15 = lane & 15, l4 = lane >> 4;
  const int brow = blockIdx.x * 256, bcol = blockIdx.y * 256;
  const short* Ab = A + (long long)brow * lda;
  const short* Bb = Bt + (long long)bcol * ldb;

  const int rr = t >> 3;                      // row within 64-row issue block
  const int gcol = ((t & 7) ^ (rr & 7)) * 8;  // swizzled source col (elements)
  const int ldsoff = wid * 512;               // shorts: wid*8 rows * 64

  const int ord_m[8] = {0, 0, 1, 1, 1, 1, 0, 0};
  const int ord_r[8] = {0, 128, 0, 64, 128, 192, 64, 192};

#define STAGE8(mat, row0, buf, ko)                                            \
  gload16(((mat) ? Bb : Ab) +                                                 \
              (long long)((row0) + rr) * ((mat) ? ldb : lda) + (ko) + gcol,   \
          &lds[buf][mat][(row0) * 64 + ldsoff])

  f32x4 acc[8][4] = {};
  const int nkt = K >> 6;  // assumed EVEN (epilogue LDS-reuse relies on it)

  // prologue: stage tile 0 into buf 0
#pragma unroll
  for (int j = 0; j < 8; ++j) STAGE8(ord_m[j], ord_r[j], 0, 0);
  asm volatile("s_waitcnt vmcnt(2)" ::: "memory");
  __builtin_amdgcn_s_barrier();

  for (int kt = 0; kt < nkt; ++kt) {
    const int buf = kt & 1, nbuf = buf ^ 1;
    const int kon = (kt + 1 < nkt ? (kt + 1) : kt) << 6;  // clamp: uniform counts
    short8 bfr[4][2];
#pragma unroll
    for (int p = 0; p < 4; ++p) {
      short8 af[2][2];
      const int arow = wm * 128 + p * 32;
#pragma unroll
      for (int mf = 0; mf < 2; ++mf)
#pragma unroll
        for (int ks = 0; ks < 2; ++ks) {
          const int row = arow + mf * 16 + l15;
          const int cs = (ks * 32 + l4 * 8) ^ ((row & 7) << 3);
          af[mf][ks] = *(const short8*)&lds[buf][0][row * 64 + cs];
        }
      if (p == 0) {
#pragma unroll
        for (int nf = 0; nf < 4; ++nf)
#pragma unroll
          for (int ks = 0; ks < 2; ++ks) {
            const int row = wn * 64 + nf * 16 + l15;
            const int cs = (ks * 32 + l4 * 8) ^ ((row & 7) << 3);
            bfr[nf][ks] = *(const short8*)&lds[buf][1][row * 64 + cs];
          }
      }
      STAGE8(ord_m[2 * p], ord_r[2 * p], nbuf, kon);
      STAGE8(ord_m[2 * p + 1], ord_r[2 * p + 1], nbuf, kon);
      __builtin_amdgcn_s_barrier();
      asm volatile("s_waitcnt lgkmcnt(0)" ::: "memory");
      __builtin_amdgcn_sched_barrier(0);
      __builtin_amdgcn_s_setprio(1);
#pragma unroll
      for (int mf = 0; mf < 2; ++mf)
#pragma unroll
        for (int nf = 0; nf < 4; ++nf) {
          acc[p * 2 + mf][nf] = __builtin_amdgcn_mfma_f32_16x16x32_bf16(
              af[mf][0], bfr[nf][0], acc[p * 2 + mf][nf], 0, 0, 0);
          acc[p * 2 + mf][nf] = __builtin_amdgcn_mfma_f32_16x16x32_bf16(
              af[mf][1], bfr[nf][1], acc[p * 2 + mf][nf], 0, 0, 0);
        }
      __builtin_amdgcn_s_setprio(0);
      if (p == 1) asm volatile("s_waitcnt vmcnt(4)" ::: "memory");
      if (p == 3) asm volatile("s_waitcnt vmcnt(2)" ::: "memory");
      __builtin_amdgcn_s_barrier();
    }
  }

  // epilogue: acc -> per-wave LDS (stride-68 f32) -> 256-B nt f32x4 stores
  {
    float* ep = (float*)&lds[1][0][0] + wid * 1088;  // 4352 B per wave
    float bb[4];
#pragma unroll
    for (int nf = 0; nf < 4; ++nf) bb[nf] = bias[bcol + wn * 64 + nf * 16 + l15];
#pragma unroll
    for (int mi = 0; mi < 8; ++mi) {
#pragma unroll
      for (int nf = 0; nf < 4; ++nf) {
        const f32x4 v = acc[mi][nf];
#pragma unroll
        for (int j = 0; j < 4; ++j)
          ep[(l4 * 4 + j) * 68 + nf * 16 + l15] = v[j] + bb[nf];
      }
#pragma unroll
      for (int i = 0; i < 4; ++i) {
        const f32x4 v = *(const f32x4*)&ep[(l4 + 4 * i) * 68 + l15 * 4];
        const int row_g = brow + wm * 128 + mi * 16 + l4 + 4 * i;
        const int col_g = bcol + wn * 64 + l15 * 4;
        __builtin_nontemporal_store(v, (f32x4*)&C[(long long)row_g * ldc + col_g]);
      }
    }
  }
#undef STAGE8
}

// ---------------------------------------------------------------------------
// 256x128-tile, 2-PHASE-per-K-tile variant (16 MFMA/phase). TRV: V slice of
// QKV written transposed into Vt via per-wave LDS staging.
// ---------------------------------------------------------------------------
template <bool RELU, bool TRV>
__global__ __launch_bounds__(512, 2) void gemm8pA2(
    const short* __restrict__ A, int lda,
    const short* __restrict__ Bt, int ldb,
    short* __restrict__ C, int ldc,
    short* __restrict__ Vt,
    const float* __restrict__ bias, int K) {
  __shared__ __align__(16) short ldsA[2][256 * 64];  // 64 KB
  __shared__ __align__(16) short ldsB[2][128 * 64];  // 32 KB
  const int t = threadIdx.x;
  const int lane = t & 63, wid = t >> 6;
  const int wm = wid >> 2, wn = wid & 3;
  const int l15 = lane & 15, l4 = lane >> 4;
  const int brow = blockIdx.x * 256, bcol = blockIdx.y * 128;
  const short* Ab = A + (long long)brow * lda;
  const short* Bb = Bt + (long long)bcol * ldb;

  const int rr = t >> 3;
  const int gcol = ((t & 7) ^ (rr & 7)) * 8;
  const int ldsoff = wid * 512;

#define SA(row0, buf, ko) \
  gload16(Ab + (long long)((row0) + rr) * lda + (ko) + gcol, &ldsA[buf][(row0) * 64 + ldsoff])
#define SB(row0, buf, ko) \
  gload16(Bb + (long long)((row0) + rr) * ldb + (ko) + gcol, &ldsB[buf][(row0) * 64 + ldsoff])

  f32x4 acc[8][2] = {};
  const int nkt = K >> 6;

  // prologue: tile 0 -> buf 0
  SA(0, 0, 0);
  SA(128, 0, 0);
  SB(0, 0, 0);
  SB(64, 0, 0);
  SA(64, 0, 0);
  SA(192, 0, 0);
  asm volatile("s_waitcnt vmcnt(2)" ::: "memory");
  __builtin_amdgcn_s_barrier();

  for (int kt = 0; kt < nkt; ++kt) {
    const int buf = kt & 1, nbuf = buf ^ 1;
    const int kon = (kt + 1 < nkt ? (kt + 1) : kt) << 6;  // clamp: uniform counts
    short8 bfr[2][2];
#pragma unroll
    for (int q = 0; q < 2; ++q) {
      short8 af[4][2];
      const int arow = wm * 128 + q * 64;
#pragma unroll
      for (int mf = 0; mf < 4; ++mf)
#pragma unroll
        for (int ks = 0; ks < 2; ++ks) {
          const int row = arow + mf * 16 + l15;
          const int cs = (ks * 32 + l4 * 8) ^ ((row & 7) << 3);
          af[mf][ks] = *(const short8*)&ldsA[buf][row * 64 + cs];
        }
      if (q == 0) {
#pragma unroll
        for (int nf = 0; nf < 2; ++nf)
#pragma unroll
          for (int ks = 0; ks < 2; ++ks) {
            const int row = wn * 32 + nf * 16 + l15;
            const int cs = (ks * 32 + l4 * 8) ^ ((row & 7) << 3);
            bfr[nf][ks] = *(const short8*)&ldsB[buf][row * 64 + cs];
          }
        SA(0, nbuf, kon);
        SA(128, nbuf, kon);
        SB(0, nbuf, kon);
      } else {
        SB(64, nbuf, kon);
        SA(64, nbuf, kon);
        SA(192, nbuf, kon);
      }
      __builtin_amdgcn_s_barrier();
      asm volatile("s_waitcnt lgkmcnt(0)" ::: "memory");
      __builtin_amdgcn_sched_barrier(0);
      __builtin_amdgcn_s_setprio(1);
#pragma unroll
      for (int mf = 0; mf < 4; ++mf)
#pragma unroll
        for (int nf = 0; nf < 2; ++nf) {
          acc[q * 4 + mf][nf] = __builtin_amdgcn_mfma_f32_16x16x32_bf16(
              af[mf][0], bfr[nf][0], acc[q * 4 + mf][nf], 0, 0, 0);
          acc[q * 4 + mf][nf] = __builtin_amdgcn_mfma_f32_16x16x32_bf16(
              af[mf][1], bfr[nf][1], acc[q * 4 + mf][nf], 0, 0, 0);
        }
      __builtin_amdgcn_s_setprio(0);
      if (q == 0) asm volatile("s_waitcnt vmcnt(3)" ::: "memory");
      else        asm volatile("s_waitcnt vmcnt(2)" ::: "memory");
      __builtin_amdgcn_s_barrier();
    }
  }

  if (TRV && bcol >= 1024) {
    // transposed epilogue -> Vt[vcol][M]
    __shared__ __align__(16) short eplds[8][2176];  // 16 cols x 136 stride
    short* ep = eplds[wid];
    const int vc0 = bcol - 1024 + wn * 32;
#pragma unroll
    for (int nf = 0; nf < 2; ++nf) {
      const float bb = bias[bcol + wn * 32 + nf * 16 + l15];
#pragma unroll
      for (int mi = 0; mi < 8; ++mi) {
        short4v pk;
#pragma unroll
        for (int j = 0; j < 4; ++j) pk[j] = f2bf(acc[mi][nf][j] + bb);
        *(short4v*)&ep[l15 * 136 + mi * 16 + l4 * 4] = pk;
      }
#pragma unroll
      for (int rd = 0; rd < 4; ++rd) {
        const int cl = rd * 4 + (lane >> 4);  // col-local 0..15
        const int rc = (lane & 15) * 8;       // row chunk
        const short8 v = *(const short8*)&ep[cl * 136 + rc];
        *(short8*)(Vt + (long long)(vc0 + nf * 16 + cl) * M_ + brow + wm * 128 + rc) = v;
      }
    }
  } else {
    // row-major bf16 epilogue
#pragma unroll
    for (int nf = 0; nf < 2; ++nf) {
      const int col = bcol + wn * 32 + nf * 16 + l15;
      const float bb = bias[col];
#pragma unroll
      for (int mi = 0; mi < 8; ++mi) {
        const int row0 = brow + wm * 128 + mi * 16 + l4 * 4;
        f32x4 v = acc[mi][nf];
#pragma unroll
        for (int j = 0; j < 4; ++j) {
          float z = v[j] + bb;
          if (RELU) z = fmaxf(z, 0.0f);
          C[(long long)(row0 + j) * ldc + col] = f2bf(z);
        }
      }
    }
  }
#undef SA
#undef SB
}

// ---------------------------------------------------------------------------
// bf16 MFMA GEMM: C[M,N] = act(A[M,K] @ Bt[N,K]^T + bias)
// Tile: 128 x BN, BK=64. T3-minimum 2-phase: double-buffered LDS, prefetch
// next tile BEFORE computing current, ONE __syncthreads per K-step (drains
// the prefetch + synchronizes LDS reuse). k-order unchanged -> bit-identical.
// FLIP: reverse bm for z==1 (causal load balance, round-10 verified).
// ---------------------------------------------------------------------------
template <int BN, int OUT_MODE, bool RELU, int CAUSAL, int BIAS_MODE, bool FLIP>
__global__ __launch_bounds__(256) void gemm_bt(
    const short* __restrict__ A, int lda, long long batchA,
    const short* __restrict__ Bt, int ldb, long long batchB,
    void* __restrict__ Cp, int ldc, long long batchC,
    void* __restrict__ Cp2, const float* __restrict__ bias, int M, int N, int K) {
  const int bz = blockIdx.z;
  const int bm = (FLIP && bz == 1) ? (gridDim.x - 1 - blockIdx.x) : blockIdx.x;
  const int bn = blockIdx.y;
  if (CAUSAL == 1 && bn * BN >= bm * 128 + 128) return;
  const int brow = bm * 128, bcol = bn * BN;
  const short* Ab = A + (long long)bz * batchA;
  const short* Bb = Bt + (long long)bz * batchB;

  const int kend = (CAUSAL == 2) ? min(K, brow + 128) : K;

  __shared__ __align__(16) short As[2][128 * 64];
  __shared__ __align__(16) short Bs[2][BN * 64];

  const int t = threadIdx.x;
  const int lane = t & 63, wid = t >> 6;
  constexpr int M_REP = (BN == 128) ? 4 : 2;
  const int wr = (BN == 128) ? (wid >> 1) : wid;
  const int wc = (BN == 128) ? (wid & 1) : 0;
  const int rbase = wr * (M_REP * 16);
  const int cbase = wc * 64;
  const int l15 = lane & 15, l4 = lane >> 4;

  f32x4 acc[M_REP][4] = {};

  auto stage = [&](int buf, int ko) {
#pragma unroll
    for (int i = 0; i < 4; i++) {
      const int c = t + i * 256;
      gload16(Ab + (long long)(brow + (c >> 3)) * lda + ko + ((c & 7) << 3),
              As[buf] + (i * 256 + wid * 64) * 8);
    }
#pragma unroll
    for (int i = 0; i < BN / 32; i++) {
      const int c = t + i * 256;
      gload16(Bb + (long long)(bcol + (c >> 3)) * ldb + ko + ((c & 7) << 3),
              Bs[buf] + (i * 256 + wid * 64) * 8);
    }
  };

  stage(0, 0);
  __syncthreads();  // drain prologue stage
  int cur = 0;
  for (int ko = 0; ko < kend; ko += 64) {
    if (ko + 64 < kend) stage(cur ^ 1, ko + 64);  // prefetch next (uniform cond)
#pragma unroll
    for (int ks = 0; ks < 2; ks++) {
      short8 af[M_REP], bfr[4];
#pragma unroll
      for (int m = 0; m < M_REP; m++)
        af[m] = *(const short8*)(As[cur] + (rbase + m * 16 + l15) * 64 + ks * 32 + l4 * 8);
#pragma unroll
      for (int n = 0; n < 4; n++)
        bfr[n] = *(const short8*)(Bs[cur] + (cbase + n * 16 + l15) * 64 + ks * 32 + l4 * 8);
#pragma unroll
      for (int m = 0; m < M_REP; m++)
#pragma unroll
        for (int n = 0; n < 4; n++)
          acc[m][n] = __builtin_amdgcn_mfma_f32_16x16x32_bf16(af[m], bfr[n], acc[m][n], 0, 0, 0);
    }
    __syncthreads();  // drains prefetch vmcnt; guards LDS reuse next iter
    cur ^= 1;
  }

  // epilogue: C/D layout col = lane&15, row = (lane>>4)*4 + reg  [m89-verified]
#pragma unroll
  for (int n = 0; n < 4; n++) {
    const int col = bcol + cbase + n * 16 + l15;
    const float bcv = (BIAS_MODE == 0 && bias) ? bias[col] : 0.0f;
#pragma unroll
    for (int m = 0; m < M_REP; m++) {
      const int row0 = brow + rbase + m * 16 + l4 * 4;
      f32x4 v = acc[m][n];
#pragma unroll
      for (int j = 0; j < 4; j++) {
        const float bb = (BIAS_MODE == 0) ? bcv : (bias ? bias[row0 + j] : 0.0f);
        float z = v[j] + bb;
        if (RELU) z = fmaxf(z, 0.0f);
        v[j] = z;
      }
      if (OUT_MODE == 0) {
        float* C = (float*)Cp + (long long)bz * batchC;
#pragma unroll
        for (int j = 0; j < 4; j++) C[(long long)(row0 + j) * ldc + col] = v[j];
      } else if (OUT_MODE == 1) {
        short* C = (short*)Cp + (long long)bz * batchC;
#pragma unroll
        for (int j = 0; j < 4; j++) C[(long long)(row0 + j) * ldc + col] = f2bf(v[j]);
      } else {  // 3: dual f32 + bf16
        float* C = (float*)Cp;
        short* C2 = (short*)Cp2;
#pragma unroll
        for (int j = 0; j < 4; j++) {
          C[(long long)(row0 + j) * ldc + col] = v[j];
          C2[(long long)(row0 + j) * ldc + col] = f2bf(v[j]);
        }
      }
    }
  }
}

// ---------------------------------------------------------------------------
// Weight prep: f32 [Z][R][C] (z-stride in_zs) -> bf16 [Z][C][R] (z-stride out_zs)
// ---------------------------------------------------------------------------
__global__ void transpose_convert(const float* __restrict__ in, short* __restrict__ out,
                                  int R, int C, long long in_zs, long long out_zs) {
  __shared__ float tile[32][33];
  in += (long long)blockIdx.z * in_zs;
  out += (long long)blockIdx.z * out_zs;
  const int c0 = blockIdx.x * 32, r0 = blockIdx.y * 32;
  const int tx = threadIdx.x, ty = threadIdx.y;
#pragma unroll
  for (int i = 0; i < 32; i += 8)
    tile[ty + i][tx] = in[(long long)(r0 + ty + i) * C + (c0 + tx)];
  __syncthreads();
#pragma unroll
  for (int i = 0; i < 32; i += 8)
    out[(long long)(c0 + ty + i) * R + (r0 + tx)] = f2bf(tile[tx][ty + i]);
}

__global__ void concat_bias3(const float* __restrict__ bq, const float* __restrict__ bk,
                             const float* __restrict__ bv, float* __restrict__ dst) {
  const int l = blockIdx.x, t = threadIdx.x;  // 1024 threads
  if (t < 512) {
    dst[(long long)l * 2048 + t] = bq[(long long)l * 512 + t];
    dst[(long long)l * 2048 + 512 + t] = bk[(long long)l * 512 + t];
  }
  dst[(long long)l * 2048 + 1024 + t] = bv[(long long)l * 1024 + t];
}

__global__ void embed_kernel(const int* __restrict__ x, const float* __restrict__ emb,
                             float* __restrict__ h32, short* __restrict__ h16) {
  const int m = blockIdx.x, t = threadIdx.x;
  const int tok = x[m];
  f32x4 v = ((const f32x4*)(emb + (long long)tok * D_))[t];
  ((f32x4*)(h32 + (long long)m * D_))[t] = v;
  short4v s;
#pragma unroll
  for (int j = 0; j < 4; j++) s[j] = f2bf(v[j]);
  ((short4v*)(h16 + (long long)m * D_))[t] = s;
}

// LDS-staged causal softmax: 1 global read of the row, exp cached in LDS.
__global__ __launch_bounds__(256) void softmax_kernel(const float* __restrict__ scores,
                                                      short* __restrict__ P) {
  __shared__ float row[S_];  // 8 KB
  __shared__ float red[8];
  const int r = blockIdx.x, b = blockIdx.y;
  const float* srow = scores + ((long long)b * S_ + r) * S_;
  short* prow = P + ((long long)b * S_ + r) * S_;
  const int t = threadIdx.x;
  const int n = r + 1;                          // valid columns
  const int nw = min(S_, ((r >> 7) + 1) << 7);  // 128-aligned write extent
  for (int c = t * 4; c < nw; c += 1024)
    *(f32x4*)(row + c) = *(const f32x4*)(srow + c);
  __syncthreads();
  float mx = -3.4e38f;
  for (int c = t; c < n; c += 256) mx = fmaxf(mx, row[c]);
  for (int off = 32; off; off >>= 1) mx = fmaxf(mx, __shfl_down(mx, off));
  const int lane = t & 63, wid = t >> 6;
  if (lane == 0) red[wid] = mx;
  __syncthreads();
  mx = fmaxf(fmaxf(red[0], red[1]), fmaxf(red[2], red[3]));
  float sum = 0.f;
  for (int c = t; c < n; c += 256) {
    const float e = __expf(row[c] - mx);
    row[c] = e;
    sum += e;
  }
  for (int off = 32; off; off >>= 1) sum += __shfl_down(sum, off);
  __syncthreads();  // red[] reuse
  if (lane == 0) red[4 + wid] = sum;
  __syncthreads();
  sum = red[4] + red[5] + red[6] + red[7];
  const float inv = 1.0f / sum;
  for (int c = t; c < nw; c += 256)
    prow[c] = f2bf((c < n) ? row[c] * inv : 0.0f);
}

__global__ __launch_bounds__(256) void ln_kernel(float* __restrict__ h32, short* __restrict__ h16,
                                                 const float* __restrict__ att,
                                                 const float* __restrict__ g,
                                                 const float* __restrict__ bb) {
  const int m = blockIdx.x, t = threadIdx.x;
  f32x4 hv = ((const f32x4*)(h32 + (long long)m * D_))[t];
  f32x4 av = ((const f32x4*)(att + (long long)m * D_))[t];
  float y[4];
  float s = 0.f, ss = 0.f;
#pragma unroll
  for (int j = 0; j < 4; j++) {
    y[j] = hv[j] + av[j];
    s += y[j];
    ss += y[j] * y[j];
  }
  for (int off = 32; off; off >>= 1) {
    s += __shfl_down(s, off);
    ss += __shfl_down(ss, off);
  }
  __shared__ float red[8];
  const int lane = t & 63, wid = t >> 6;
  if (lane == 0) {
    red[wid] = s;
    red[4 + wid] = ss;
  }
  __syncthreads();
  s = red[0] + red[1] + red[2] + red[3];
  ss = red[4] + red[5] + red[6] + red[7];
  const float mu = s * (1.0f / D_);
  const float var = ss * (1.0f / D_) - mu * mu;
  const float inv = rsqrtf(var + 1e-5f);
  f32x4 gv = ((const f32x4*)g)[t];
  f32x4 bv = ((const f32x4*)bb)[t];
  f32x4 o;
  short4v ob;
#pragma unroll
  for (int j = 0; j < 4; j++) {
    const float z = (y[j] - mu) * inv * gv[j] + bv[j];
    o[j] = z;
    ob[j] = f2bf(z);
  }
  ((f32x4*)(h32 + (long long)m * D_))[t] = o;
  ((short4v*)(h16 + (long long)m * D_))[t] = ob;
}

// ---------------------------------------------------------------------------
extern "C" void kernel_launch(void* const* d_in, const int* in_sizes, int n_in,
                              void* d_out, int out_size, void* d_ws, size_t ws_size,
                              hipStream_t stream) {
  const int* x = (const int*)d_in[0];
  const float* emb = (const float*)d_in[1];
  const float* Wq = (const float*)d_in[2];
  const float* bq = (const float*)d_in[3];
  const float* Wk = (const float*)d_in[4];
  const float* bk = (const float*)d_in[5];
  const float* Wv = (const float*)d_in[6];
  const float* bv = (const float*)d_in[7];
  const float* ln_g = (const float*)d_in[8];
  const float* ln_b = (const float*)d_in[9];
  const float* W1 = (const float*)d_in[10];
  const float* b1 = (const float*)d_in[11];
  const float* W2 = (const float*)d_in[12];
  const float* b2 = (const float*)d_in[13];
  const float* Wout = (const float*)d_in[14];
  const float* bout = (const float*)d_in[15];
  float* out = (float*)d_out;

  char* p = (char*)d_ws;
  auto alloc = [&](long long bytes) -> char* {
    char* r = p;
    p += (bytes + 255) & ~255LL;
    return r;
  };
  // wqkv packed [L][2048 rows (q:0-511, k:512-1023, v:1024-2047)][D]
  short* wqkv_t = (short*)alloc((long long)L_ * 2048 * D_ * 2);
  short* w1_t = (short*)alloc((long long)L_ * DFF_ * D_ * 2);
  short* w2_t = (short*)alloc((long long)L_ * D_ * DFF_ * 2);
  short* wout_t = (short*)alloc((long long)V_ * D_ * 2);
  float* bqkv = (float*)alloc((long long)L_ * 2048 * 4);
  short* h16 = (short*)alloc((long long)M_ * D_ * 2);
  float* h32 = (float*)alloc((long long)M_ * D_ * 4);
  short* qkv = (short*)alloc((long long)M_ * 2048 * 2);  // [4096][2048] q|k|(v unused)
  short* vt = (short*)alloc((long long)D_ * M_ * 2);     // [1024][4096]
  float* sc = (float*)alloc((long long)B_ * S_ * S_ * 4);
  short* Pm = (short*)alloc((long long)B_ * S_ * S_ * 2);
  float* att32 = (float*)alloc((long long)M_ * D_ * 4);
  short* mid = (short*)alloc((long long)M_ * DFF_ * 2);

  const dim3 tb(32, 8);
  const long long qkv_zs = (long long)2048 * D_;
  transpose_convert<<<dim3(DA_ / 32, D_ / 32, L_), tb, 0, stream>>>(
      Wq, wqkv_t, D_, DA_, (long long)D_ * DA_, qkv_zs);
  transpose_convert<<<dim3(DA_ / 32, D_ / 32, L_), tb, 0, stream>>>(
      Wk, wqkv_t + (long long)DA_ * D_, D_, DA_, (long long)D_ * DA_, qkv_zs);
  transpose_convert<<<dim3(D_ / 32, D_ / 32, L_), tb, 0, stream>>>(
      Wv, wqkv_t + (long long)D_ * D_, D_, D_, (long long)D_ * D_, qkv_zs);
  transpose_convert<<<dim3(DFF_ / 32, D_ / 32, L_), tb, 0, stream>>>(
      W1, w1_t, D_, DFF_, (long long)D_ * DFF_, (long long)D_ * DFF_);
  transpose_convert<<<dim3(D_ / 32, DFF_ / 32, L_), tb, 0, stream>>>(
      W2, w2_t, DFF_, D_, (long long)DFF_ * D_, (long long)DFF_ * D_);
  transpose_convert<<<dim3(V_ / 32, D_ / 32, 1), tb, 0, stream>>>(
      Wout, wout_t, D_, V_, (long long)D_ * V_, (long long)D_ * V_);
  concat_bias3<<<L_, 1024, 0, stream>>>(bq, bk, bv, bqkv);

  embed_kernel<<<M_, 256, 0, stream>>>(x, emb, h32, h16);

  for (int i = 0; i < L_; i++) {
    const short* wqkv_l = wqkv_t + (long long)i * qkv_zs;
    const short* w1_l = w1_t + (long long)i * DFF_ * D_;
    const short* w2_l = w2_t + (long long)i * D_ * DFF_;

    // QKV (8-phase 2ph/K-tile, 256 blocks); V slice written transposed -> vt
    gemm8pA2<false, true><<<dim3(M_ / 256, 2048 / 128), 512, 0, stream>>>(
        h16, D_, wqkv_l, D_, qkv, 2048, vt, bqkv + (long long)i * 2048, D_);
    // scores[b] = Q[b] @ K[b]^T  f32, causal tile-skip, z-flip balanced
    gemm_bt<64, 0, false, 1, 0, true><<<dim3(S_ / 128, S_ / 64, B_), 256, 0, stream>>>(
        qkv, 2048, (long long)S_ * 2048, qkv + DA_, 2048, (long long)S_ * 2048,
        sc, S_, (long long)S_ * S_, nullptr, nullptr, S_, S_, DA_);
    // causal softmax -> P bf16 (zeros up to diagonal tile edge)
    softmax_kernel<<<dim3(S_, B_), 256, 0, stream>>>(sc, Pm);
    // att[b] = P[b] @ V[b]  f32, k-loop clipped, z-flip balanced
    gemm_bt<64, 0, false, 2, 0, true><<<dim3(S_ / 128, D_ / 64, B_), 256, 0, stream>>>(
        Pm, S_, (long long)S_ * S_, vt, M_, (long long)S_, att32, D_,
        (long long)S_ * D_, nullptr, nullptr, S_, D_, S_);
    // h = LN(h + att)  (f32 master + bf16 shadow)
    ln_kernel<<<M_, 256, 0, stream>>>(h32, h16, att32, ln_g + (long long)i * D_,
                                      ln_b + (long long)i * D_);
    // mid = relu(h @ W1 + b1)  bf16  (8-phase 2ph/K-tile, 256 blocks)
    gemm8pA2<true, false><<<dim3(M_ / 256, DFF_ / 128), 512, 0, stream>>>(
        h16, D_, w1_l, D_, mid, DFF_, nullptr, b1 + (long long)i * DFF_, D_);
    // h = mid @ W2 + b2 -> f32 master + bf16 shadow  (2-phase dbuf, 512 blocks)
    gemm_bt<64, 3, false, 0, 0, false><<<dim3(M_ / 128, D_ / 64, 1), 256, 0, stream>>>(
        mid, DFF_, 0, w2_l, DFF_, 0, h32, D_, 0, h16,
        b2 + (long long)i * D_, M_, D_, DFF_);
  }

  // logits = h @ Wout + bout  f32 -> d_out  (256^2 8-phase, 2000 blocks)
  gemm8p<<<dim3(M_ / 256, V_ / 256), 512, 0, stream>>>(
      h16, D_, wout_t, D_, out, V_, bout, D_);
}

// Round 13
// 2487.555 us; speedup vs baseline: 1.1088x; 1.0178x over previous
//
#include <hip/hip_runtime.h>
#include <stdint.h>

#define B_   2
#define S_   2048
#define D_   1024
#define DA_  512
#define DFF_ 2048
#define V_   32000
#define L_   12
#define M_   (B_ * S_)  // 4096

typedef __attribute__((ext_vector_type(4))) float f32x4;
typedef __attribute__((ext_vector_type(8))) short short8;
typedef __attribute__((ext_vector_type(4))) short short4v;

__device__ __forceinline__ short f2bf(float f) {
  uint32_t u = __float_as_uint(f);
  u += 0x7fffu + ((u >> 16) & 1u);
  return (short)(u >> 16);
}

__device__ __forceinline__ void gload16(const short* g, short* l) {
  __builtin_amdgcn_global_load_lds(
      (const __attribute__((address_space(1))) char*)g,
      (__attribute__((address_space(3))) char*)l, 16, 0, 0);
}

// ---------------------------------------------------------------------------
// 256x256 8-phase bf16 GEMM (T2 swizzle + T3/T4 counted vmcnt + T5 setprio).
// ---------------------------------------------------------------------------
__global__ __launch_bounds__(512, 2) void gemm8p(
    const short* __restrict__ A, int lda,
    const short* __restrict__ Bt, int ldb,
    float* __restrict__ C, int ldc,
    const float* __restrict__ bias, int K) {
  __shared__ __align__(16) short lds[2][2][256 * 64];  // [buf][A=0/B=1][row*64+c]
  const int t = threadIdx.x;
  const int lane = t & 63, wid = t >> 6;
  const int wm = wid >> 2, wn = wid & 3;
  const int l15 = lane & 15, l4 = lane >> 4;
  const int brow = blockIdx.x * 256, bcol = blockIdx.y * 256;
  const short* Ab = A + (long long)brow * lda;
  const short* Bb = Bt + (long long)bcol * ldb;

  const int rr = t >> 3;                      // row within 64-row issue block
  const int gcol = ((t & 7) ^ (rr & 7)) * 8;  // swizzled source col (elements)
  const int ldsoff = wid * 512;               // shorts: wid*8 rows * 64

  const int ord_m[8] = {0, 0, 1, 1, 1, 1, 0, 0};
  const int ord_r[8] = {0, 128, 0, 64, 128, 192, 64, 192};

#define STAGE8(mat, row0, buf, ko)                                            \
  gload16(((mat) ? Bb : Ab) +                                                 \
              (long long)((row0) + rr) * ((mat) ? ldb : lda) + (ko) + gcol,   \
          &lds[buf][mat][(row0) * 64 + ldsoff])

  f32x4 acc[8][4] = {};
  const int nkt = K >> 6;  // assumed EVEN (epilogue LDS-reuse relies on it)

  // prologue: stage tile 0 into buf 0
#pragma unroll
  for (int j = 0; j < 8; ++j) STAGE8(ord_m[j], ord_r[j], 0, 0);
  asm volatile("s_waitcnt vmcnt(2)" ::: "memory");
  __builtin_amdgcn_s_barrier();

  for (int kt = 0; kt < nkt; ++kt) {
    const int buf = kt & 1, nbuf = buf ^ 1;
    const int kon = (kt + 1 < nkt ? (kt + 1) : kt) << 6;  // clamp: uniform counts
    short8 bfr[4][2];
#pragma unroll
    for (int p = 0; p < 4; ++p) {
      short8 af[2][2];
      const int arow = wm * 128 + p * 32;
#pragma unroll
      for (int mf = 0; mf < 2; ++mf)
#pragma unroll
        for (int ks = 0; ks < 2; ++ks) {
          const int row = arow + mf * 16 + l15;
          const int cs = (ks * 32 + l4 * 8) ^ ((row & 7) << 3);
          af[mf][ks] = *(const short8*)&lds[buf][0][row * 64 + cs];
        }
      if (p == 0) {
#pragma unroll
        for (int nf = 0; nf < 4; ++nf)
#pragma unroll
          for (int ks = 0; ks < 2; ++ks) {
            const int row = wn * 64 + nf * 16 + l15;
            const int cs = (ks * 32 + l4 * 8) ^ ((row & 7) << 3);
            bfr[nf][ks] = *(const short8*)&lds[buf][1][row * 64 + cs];
          }
      }
      STAGE8(ord_m[2 * p], ord_r[2 * p], nbuf, kon);
      STAGE8(ord_m[2 * p + 1], ord_r[2 * p + 1], nbuf, kon);
      __builtin_amdgcn_s_barrier();
      asm volatile("s_waitcnt lgkmcnt(0)" ::: "memory");
      __builtin_amdgcn_sched_barrier(0);
      __builtin_amdgcn_s_setprio(1);
#pragma unroll
      for (int mf = 0; mf < 2; ++mf)
#pragma unroll
        for (int nf = 0; nf < 4; ++nf) {
          acc[p * 2 + mf][nf] = __builtin_amdgcn_mfma_f32_16x16x32_bf16(
              af[mf][0], bfr[nf][0], acc[p * 2 + mf][nf], 0, 0, 0);
          acc[p * 2 + mf][nf] = __builtin_amdgcn_mfma_f32_16x16x32_bf16(
              af[mf][1], bfr[nf][1], acc[p * 2 + mf][nf], 0, 0, 0);
        }
      __builtin_amdgcn_s_setprio(0);
      if (p == 1) asm volatile("s_waitcnt vmcnt(4)" ::: "memory");
      if (p == 3) asm volatile("s_waitcnt vmcnt(2)" ::: "memory");
      __builtin_amdgcn_s_barrier();
    }
  }

  // epilogue: acc -> per-wave LDS (stride-68 f32) -> 256-B nt f32x4 stores
  {
    float* ep = (float*)&lds[1][0][0] + wid * 1088;  // 4352 B per wave
    float bb[4];
#pragma unroll
    for (int nf = 0; nf < 4; ++nf) bb[nf] = bias[bcol + wn * 64 + nf * 16 + l15];
#pragma unroll
    for (int mi = 0; mi < 8; ++mi) {
#pragma unroll
      for (int nf = 0; nf < 4; ++nf) {
        const f32x4 v = acc[mi][nf];
#pragma unroll
        for (int j = 0; j < 4; ++j)
          ep[(l4 * 4 + j) * 68 + nf * 16 + l15] = v[j] + bb[nf];
      }
#pragma unroll
      for (int i = 0; i < 4; ++i) {
        const f32x4 v = *(const f32x4*)&ep[(l4 + 4 * i) * 68 + l15 * 4];
        const int row_g = brow + wm * 128 + mi * 16 + l4 + 4 * i;
        const int col_g = bcol + wn * 64 + l15 * 4;
        __builtin_nontemporal_store(v, (f32x4*)&C[(long long)row_g * ldc + col_g]);
      }
    }
  }
#undef STAGE8
}

// ---------------------------------------------------------------------------
// 256x128-tile, 2-PHASE-per-K-tile variant (16 MFMA/phase). TRV: V slice of
// QKV written transposed into Vt via per-wave LDS staging. Row-major path
// uses an LDS-staged wide-store epilogue (64-B contiguous short8 stores).
// ---------------------------------------------------------------------------
template <bool RELU, bool TRV>
__global__ __launch_bounds__(512, 2) void gemm8pA2(
    const short* __restrict__ A, int lda,
    const short* __restrict__ Bt, int ldb,
    short* __restrict__ C, int ldc,
    short* __restrict__ Vt,
    const float* __restrict__ bias, int K) {
  __shared__ __align__(16) short ldsA[2][256 * 64];  // 64 KB
  __shared__ __align__(16) short ldsB[2][128 * 64];  // 32 KB
  const int t = threadIdx.x;
  const int lane = t & 63, wid = t >> 6;
  const int wm = wid >> 2, wn = wid & 3;
  const int l15 = lane & 15, l4 = lane >> 4;
  const int brow = blockIdx.x * 256, bcol = blockIdx.y * 128;
  const short* Ab = A + (long long)brow * lda;
  const short* Bb = Bt + (long long)bcol * ldb;

  const int rr = t >> 3;
  const int gcol = ((t & 7) ^ (rr & 7)) * 8;
  const int ldsoff = wid * 512;

#define SA(row0, buf, ko) \
  gload16(Ab + (long long)((row0) + rr) * lda + (ko) + gcol, &ldsA[buf][(row0) * 64 + ldsoff])
#define SB(row0, buf, ko) \
  gload16(Bb + (long long)((row0) + rr) * ldb + (ko) + gcol, &ldsB[buf][(row0) * 64 + ldsoff])

  f32x4 acc[8][2] = {};
  const int nkt = K >> 6;  // EVEN (epilogue ldsB[1]-reuse relies on it)

  // prologue: tile 0 -> buf 0
  SA(0, 0, 0);
  SA(128, 0, 0);
  SB(0, 0, 0);
  SB(64, 0, 0);
  SA(64, 0, 0);
  SA(192, 0, 0);
  asm volatile("s_waitcnt vmcnt(2)" ::: "memory");
  __builtin_amdgcn_s_barrier();

  for (int kt = 0; kt < nkt; ++kt) {
    const int buf = kt & 1, nbuf = buf ^ 1;
    const int kon = (kt + 1 < nkt ? (kt + 1) : kt) << 6;  // clamp: uniform counts
    short8 bfr[2][2];
#pragma unroll
    for (int q = 0; q < 2; ++q) {
      short8 af[4][2];
      const int arow = wm * 128 + q * 64;
#pragma unroll
      for (int mf = 0; mf < 4; ++mf)
#pragma unroll
        for (int ks = 0; ks < 2; ++ks) {
          const int row = arow + mf * 16 + l15;
          const int cs = (ks * 32 + l4 * 8) ^ ((row & 7) << 3);
          af[mf][ks] = *(const short8*)&ldsA[buf][row * 64 + cs];
        }
      if (q == 0) {
#pragma unroll
        for (int nf = 0; nf < 2; ++nf)
#pragma unroll
          for (int ks = 0; ks < 2; ++ks) {
            const int row = wn * 32 + nf * 16 + l15;
            const int cs = (ks * 32 + l4 * 8) ^ ((row & 7) << 3);
            bfr[nf][ks] = *(const short8*)&ldsB[buf][row * 64 + cs];
          }
        SA(0, nbuf, kon);
        SA(128, nbuf, kon);
        SB(0, nbuf, kon);
      } else {
        SB(64, nbuf, kon);
        SA(64, nbuf, kon);
        SA(192, nbuf, kon);
      }
      __builtin_amdgcn_s_barrier();
      asm volatile("s_waitcnt lgkmcnt(0)" ::: "memory");
      __builtin_amdgcn_sched_barrier(0);
      __builtin_amdgcn_s_setprio(1);
#pragma unroll
      for (int mf = 0; mf < 4; ++mf)
#pragma unroll
        for (int nf = 0; nf < 2; ++nf) {
          acc[q * 4 + mf][nf] = __builtin_amdgcn_mfma_f32_16x16x32_bf16(
              af[mf][0], bfr[nf][0], acc[q * 4 + mf][nf], 0, 0, 0);
          acc[q * 4 + mf][nf] = __builtin_amdgcn_mfma_f32_16x16x32_bf16(
              af[mf][1], bfr[nf][1], acc[q * 4 + mf][nf], 0, 0, 0);
        }
      __builtin_amdgcn_s_setprio(0);
      if (q == 0) asm volatile("s_waitcnt vmcnt(3)" ::: "memory");
      else        asm volatile("s_waitcnt vmcnt(2)" ::: "memory");
      __builtin_amdgcn_s_barrier();
    }
  }

  if (TRV && bcol >= 1024) {
    // transposed epilogue -> Vt[vcol][M]
    __shared__ __align__(16) short eplds[8][2176];  // 16 cols x 136 stride
    short* ep = eplds[wid];
    const int vc0 = bcol - 1024 + wn * 32;
#pragma unroll
    for (int nf = 0; nf < 2; ++nf) {
      const float bb = bias[bcol + wn * 32 + nf * 16 + l15];
#pragma unroll
      for (int mi = 0; mi < 8; ++mi) {
        short4v pk;
#pragma unroll
        for (int j = 0; j < 4; ++j) pk[j] = f2bf(acc[mi][nf][j] + bb);
        *(short4v*)&ep[l15 * 136 + mi * 16 + l4 * 4] = pk;
      }
#pragma unroll
      for (int rd = 0; rd < 4; ++rd) {
        const int cl = rd * 4 + (lane >> 4);  // col-local 0..15
        const int rc = (lane & 15) * 8;       // row chunk
        const short8 v = *(const short8*)&ep[cl * 136 + rc];
        *(short8*)(Vt + (long long)(vc0 + nf * 16 + cl) * M_ + brow + wm * 128 + rc) = v;
      }
    }
  } else {
    // LDS-staged wide-store epilogue: per-wave 16 rows x 48-short (96 B,
    // 16-B aligned) region in ldsB[1]. Safe: nkt even -> final in-flight
    // DMAs target buf 0 only; loop ended with s_barrier so all waves are
    // past their ldsB[1] reads. Stores: 64-B contiguous short8 per row.
    short* ep = &ldsB[1][wid * 768];  // 16*48 shorts = 1536 B per wave
    const int rr2 = lane >> 2;        // read row 0..15
    const int ch = lane & 3;          // read chunk (8 shorts)
    float bb[2];
#pragma unroll
    for (int nf = 0; nf < 2; ++nf) bb[nf] = bias[bcol + wn * 32 + nf * 16 + l15];
#pragma unroll
    for (int mi = 0; mi < 8; ++mi) {
#pragma unroll
      for (int nf = 0; nf < 2; ++nf) {
        const f32x4 v = acc[mi][nf];
#pragma unroll
        for (int j = 0; j < 4; ++j) {
          float z = v[j] + bb[nf];
          if (RELU) z = fmaxf(z, 0.0f);
          ep[(l4 * 4 + j) * 48 + nf * 16 + l15] = f2bf(z);
        }
      }
      const short8 w8 = *(const short8*)&ep[rr2 * 48 + ch * 8];
      const int row_g = brow + wm * 128 + mi * 16 + rr2;
      const int col_g = bcol + wn * 32 + ch * 8;
      *(short8*)(C + (long long)row_g * ldc + col_g) = w8;
    }
  }
#undef SA
#undef SB
}

// ---------------------------------------------------------------------------
// bf16 MFMA GEMM: C[M,N] = act(A[M,K] @ Bt[N,K]^T + bias)
// Tile: 128 x BN, BK=64. T3-minimum 2-phase: double-buffered LDS, prefetch
// next tile BEFORE computing current, ONE __syncthreads per K-step.
// FLIP: reverse bm for z==1 (causal load balance, round-10 verified).
// ---------------------------------------------------------------------------
template <int BN, int OUT_MODE, bool RELU, int CAUSAL, int BIAS_MODE, bool FLIP>
__global__ __launch_bounds__(256) void gemm_bt(
    const short* __restrict__ A, int lda, long long batchA,
    const short* __restrict__ Bt, int ldb, long long batchB,
    void* __restrict__ Cp, int ldc, long long batchC,
    void* __restrict__ Cp2, const float* __restrict__ bias, int M, int N, int K) {
  const int bz = blockIdx.z;
  const int bm = (FLIP && bz == 1) ? (gridDim.x - 1 - blockIdx.x) : blockIdx.x;
  const int bn = blockIdx.y;
  if (CAUSAL == 1 && bn * BN >= bm * 128 + 128) return;
  const int brow = bm * 128, bcol = bn * BN;
  const short* Ab = A + (long long)bz * batchA;
  const short* Bb = Bt + (long long)bz * batchB;

  const int kend = (CAUSAL == 2) ? min(K, brow + 128) : K;

  __shared__ __align__(16) short As[2][128 * 64];
  __shared__ __align__(16) short Bs[2][BN * 64];

  const int t = threadIdx.x;
  const int lane = t & 63, wid = t >> 6;
  constexpr int M_REP = (BN == 128) ? 4 : 2;
  const int wr = (BN == 128) ? (wid >> 1) : wid;
  const int wc = (BN == 128) ? (wid & 1) : 0;
  const int rbase = wr * (M_REP * 16);
  const int cbase = wc * 64;
  const int l15 = lane & 15, l4 = lane >> 4;

  f32x4 acc[M_REP][4] = {};

  auto stage = [&](int buf, int ko) {
#pragma unroll
    for (int i = 0; i < 4; i++) {
      const int c = t + i * 256;
      gload16(Ab + (long long)(brow + (c >> 3)) * lda + ko + ((c & 7) << 3),
              As[buf] + (i * 256 + wid * 64) * 8);
    }
#pragma unroll
    for (int i = 0; i < BN / 32; i++) {
      const int c = t + i * 256;
      gload16(Bb + (long long)(bcol + (c >> 3)) * ldb + ko + ((c & 7) << 3),
              Bs[buf] + (i * 256 + wid * 64) * 8);
    }
  };

  stage(0, 0);
  __syncthreads();  // drain prologue stage
  int cur = 0;
  for (int ko = 0; ko < kend; ko += 64) {
    if (ko + 64 < kend) stage(cur ^ 1, ko + 64);  // prefetch next (uniform cond)
#pragma unroll
    for (int ks = 0; ks < 2; ks++) {
      short8 af[M_REP], bfr[4];
#pragma unroll
      for (int m = 0; m < M_REP; m++)
        af[m] = *(const short8*)(As[cur] + (rbase + m * 16 + l15) * 64 + ks * 32 + l4 * 8);
#pragma unroll
      for (int n = 0; n < 4; n++)
        bfr[n] = *(const short8*)(Bs[cur] + (cbase + n * 16 + l15) * 64 + ks * 32 + l4 * 8);
#pragma unroll
      for (int m = 0; m < M_REP; m++)
#pragma unroll
        for (int n = 0; n < 4; n++)
          acc[m][n] = __builtin_amdgcn_mfma_f32_16x16x32_bf16(af[m], bfr[n], acc[m][n], 0, 0, 0);
    }
    __syncthreads();  // drains prefetch vmcnt; guards LDS reuse next iter
    cur ^= 1;
  }

  // epilogue: C/D layout col = lane&15, row = (lane>>4)*4 + reg  [m89-verified]
#pragma unroll
  for (int n = 0; n < 4; n++) {
    const int col = bcol + cbase + n * 16 + l15;
    const float bcv = (BIAS_MODE == 0 && bias) ? bias[col] : 0.0f;
#pragma unroll
    for (int m = 0; m < M_REP; m++) {
      const int row0 = brow + rbase + m * 16 + l4 * 4;
      f32x4 v = acc[m][n];
#pragma unroll
      for (int j = 0; j < 4; j++) {
        const float bb = (BIAS_MODE == 0) ? bcv : (bias ? bias[row0 + j] : 0.0f);
        float z = v[j] + bb;
        if (RELU) z = fmaxf(z, 0.0f);
        v[j] = z;
      }
      if (OUT_MODE == 0) {
        float* C = (float*)Cp + (long long)bz * batchC;
#pragma unroll
        for (int j = 0; j < 4; j++) C[(long long)(row0 + j) * ldc + col] = v[j];
      } else if (OUT_MODE == 1) {
        short* C = (short*)Cp + (long long)bz * batchC;
#pragma unroll
        for (int j = 0; j < 4; j++) C[(long long)(row0 + j) * ldc + col] = f2bf(v[j]);
      } else {  // 3: dual f32 + bf16
        float* C = (float*)Cp;
        short* C2 = (short*)Cp2;
#pragma unroll
        for (int j = 0; j < 4; j++) {
          C[(long long)(row0 + j) * ldc + col] = v[j];
          C2[(long long)(row0 + j) * ldc + col] = f2bf(v[j]);
        }
      }
    }
  }
}

// ---------------------------------------------------------------------------
// Weight prep: f32 [Z][R][C] (z-stride in_zs) -> bf16 [Z][C][R] (z-stride out_zs)
// ---------------------------------------------------------------------------
__global__ void transpose_convert(const float* __restrict__ in, short* __restrict__ out,
                                  int R, int C, long long in_zs, long long out_zs) {
  __shared__ float tile[32][33];
  in += (long long)blockIdx.z * in_zs;
  out += (long long)blockIdx.z * out_zs;
  const int c0 = blockIdx.x * 32, r0 = blockIdx.y * 32;
  const int tx = threadIdx.x, ty = threadIdx.y;
#pragma unroll
  for (int i = 0; i < 32; i += 8)
    tile[ty + i][tx] = in[(long long)(r0 + ty + i) * C + (c0 + tx)];
  __syncthreads();
#pragma unroll
  for (int i = 0; i < 32; i += 8)
    out[(long long)(c0 + ty + i) * R + (r0 + tx)] = f2bf(tile[tx][ty + i]);
}

__global__ void concat_bias3(const float* __restrict__ bq, const float* __restrict__ bk,
                             const float* __restrict__ bv, float* __restrict__ dst) {
  const int l = blockIdx.x, t = threadIdx.x;  // 1024 threads
  if (t < 512) {
    dst[(long long)l * 2048 + t] = bq[(long long)l * 512 + t];
    dst[(long long)l * 2048 + 512 + t] = bk[(long long)l * 512 + t];
  }
  dst[(long long)l * 2048 + 1024 + t] = bv[(long long)l * 1024 + t];
}

__global__ void embed_kernel(const int* __restrict__ x, const float* __restrict__ emb,
                             float* __restrict__ h32, short* __restrict__ h16) {
  const int m = blockIdx.x, t = threadIdx.x;
  const int tok = x[m];
  f32x4 v = ((const f32x4*)(emb + (long long)tok * D_))[t];
  ((f32x4*)(h32 + (long long)m * D_))[t] = v;
  short4v s;
#pragma unroll
  for (int j = 0; j < 4; j++) s[j] = f2bf(v[j]);
  ((short4v*)(h16 + (long long)m * D_))[t] = s;
}

// LDS-staged causal softmax: 1 global read of the row, exp cached in LDS.
__global__ __launch_bounds__(256) void softmax_kernel(const float* __restrict__ scores,
                                                      short* __restrict__ P) {
  __shared__ float row[S_];  // 8 KB
  __shared__ float red[8];
  const int r = blockIdx.x, b = blockIdx.y;
  const float* srow = scores + ((long long)b * S_ + r) * S_;
  short* prow = P + ((long long)b * S_ + r) * S_;
  const int t = threadIdx.x;
  const int n = r + 1;                          // valid columns
  const int nw = min(S_, ((r >> 7) + 1) << 7);  // 128-aligned write extent
  for (int c = t * 4; c < nw; c += 1024)
    *(f32x4*)(row + c) = *(const f32x4*)(srow + c);
  __syncthreads();
  float mx = -3.4e38f;
  for (int c = t; c < n; c += 256) mx = fmaxf(mx, row[c]);
  for (int off = 32; off; off >>= 1) mx = fmaxf(mx, __shfl_down(mx, off));
  const int lane = t & 63, wid = t >> 6;
  if (lane == 0) red[wid] = mx;
  __syncthreads();
  mx = fmaxf(fmaxf(red[0], red[1]), fmaxf(red[2], red[3]));
  float sum = 0.f;
  for (int c = t; c < n; c += 256) {
    const float e = __expf(row[c] - mx);
    row[c] = e;
    sum += e;
  }
  for (int off = 32; off; off >>= 1) sum += __shfl_down(sum, off);
  __syncthreads();  // red[] reuse
  if (lane == 0) red[4 + wid] = sum;
  __syncthreads();
  sum = red[4] + red[5] + red[6] + red[7];
  const float inv = 1.0f / sum;
  for (int c = t; c < nw; c += 256)
    prow[c] = f2bf((c < n) ? row[c] * inv : 0.0f);
}

// LN(h+att): writes bf16 shadow only. The f32 result is DEAD in this network
// (ffn2 overwrites h32 before anyone reads LN's f32 output — no post-FFN
// residual in the reference), so the h32 store is elided.
__global__ __launch_bounds__(256) void ln_kernel(const float* __restrict__ h32,
                                                 short* __restrict__ h16,
                                                 const float* __restrict__ att,
                                                 const float* __restrict__ g,
                                                 const float* __restrict__ bb) {
  const int m = blockIdx.x, t = threadIdx.x;
  f32x4 hv = ((const f32x4*)(h32 + (long long)m * D_))[t];
  f32x4 av = ((const f32x4*)(att + (long long)m * D_))[t];
  float y[4];
  float s = 0.f, ss = 0.f;
#pragma unroll
  for (int j = 0; j < 4; j++) {
    y[j] = hv[j] + av[j];
    s += y[j];
    ss += y[j] * y[j];
  }
  for (int off = 32; off; off >>= 1) {
    s += __shfl_down(s, off);
    ss += __shfl_down(ss, off);
  }
  __shared__ float red[8];
  const int lane = t & 63, wid = t >> 6;
  if (lane == 0) {
    red[wid] = s;
    red[4 + wid] = ss;
  }
  __syncthreads();
  s = red[0] + red[1] + red[2] + red[3];
  ss = red[4] + red[5] + red[6] + red[7];
  const float mu = s * (1.0f / D_);
  const float var = ss * (1.0f / D_) - mu * mu;
  const float inv = rsqrtf(var + 1e-5f);
  f32x4 gv = ((const f32x4*)g)[t];
  f32x4 bv = ((const f32x4*)bb)[t];
  short4v ob;
#pragma unroll
  for (int j = 0; j < 4; j++)
    ob[j] = f2bf((y[j] - mu) * inv * gv[j] + bv[j]);
  ((short4v*)(h16 + (long long)m * D_))[t] = ob;
}

// ---------------------------------------------------------------------------
extern "C" void kernel_launch(void* const* d_in, const int* in_sizes, int n_in,
                              void* d_out, int out_size, void* d_ws, size_t ws_size,
                              hipStream_t stream) {
  const int* x = (const int*)d_in[0];
  const float* emb = (const float*)d_in[1];
  const float* Wq = (const float*)d_in[2];
  const float* bq = (const float*)d_in[3];
  const float* Wk = (const float*)d_in[4];
  const float* bk = (const float*)d_in[5];
  const float* Wv = (const float*)d_in[6];
  const float* bv = (const float*)d_in[7];
  const float* ln_g = (const float*)d_in[8];
  const float* ln_b = (const float*)d_in[9];
  const float* W1 = (const float*)d_in[10];
  const float* b1 = (const float*)d_in[11];
  const float* W2 = (const float*)d_in[12];
  const float* b2 = (const float*)d_in[13];
  const float* Wout = (const float*)d_in[14];
  const float* bout = (const float*)d_in[15];
  float* out = (float*)d_out;

  char* p = (char*)d_ws;
  auto alloc = [&](long long bytes) -> char* {
    char* r = p;
    p += (bytes + 255) & ~255LL;
    return r;
  };
  // wqkv packed [L][2048 rows (q:0-511, k:512-1023, v:1024-2047)][D]
  short* wqkv_t = (short*)alloc((long long)L_ * 2048 * D_ * 2);
  short* w1_t = (short*)alloc((long long)L_ * DFF_ * D_ * 2);
  short* w2_t = (short*)alloc((long long)L_ * D_ * DFF_ * 2);
  short* wout_t = (short*)alloc((long long)V_ * D_ * 2);
  float* bqkv = (float*)alloc((long long)L_ * 2048 * 4);
  short* h16 = (short*)alloc((long long)M_ * D_ * 2);
  float* h32 = (float*)alloc((long long)M_ * D_ * 4);
  short* qkv = (short*)alloc((long long)M_ * 2048 * 2);  // [4096][2048] q|k|(v unused)
  short* vt = (short*)alloc((long long)D_ * M_ * 2);     // [1024][4096]
  float* sc = (float*)alloc((long long)B_ * S_ * S_ * 4);
  short* Pm = (short*)alloc((long long)B_ * S_ * S_ * 2);
  float* att32 = (float*)alloc((long long)M_ * D_ * 4);
  short* mid = (short*)alloc((long long)M_ * DFF_ * 2);

  const dim3 tb(32, 8);
  const long long qkv_zs = (long long)2048 * D_;
  transpose_convert<<<dim3(DA_ / 32, D_ / 32, L_), tb, 0, stream>>>(
      Wq, wqkv_t, D_, DA_, (long long)D_ * DA_, qkv_zs);
  transpose_convert<<<dim3(DA_ / 32, D_ / 32, L_), tb, 0, stream>>>(
      Wk, wqkv_t + (long long)DA_ * D_, D_, DA_, (long long)D_ * DA_, qkv_zs);
  transpose_convert<<<dim3(D_ / 32, D_ / 32, L_), tb, 0, stream>>>(
      Wv, wqkv_t + (long long)D_ * D_, D_, D_, (long long)D_ * D_, qkv_zs);
  transpose_convert<<<dim3(DFF_ / 32, D_ / 32, L_), tb, 0, stream>>>(
      W1, w1_t, D_, DFF_, (long long)D_ * DFF_, (long long)D_ * DFF_);
  transpose_convert<<<dim3(D_ / 32, DFF_ / 32, L_), tb, 0, stream>>>(
      W2, w2_t, DFF_, D_, (long long)DFF_ * D_, (long long)DFF_ * D_);
  transpose_convert<<<dim3(V_ / 32, D_ / 32, 1), tb, 0, stream>>>(
      Wout, wout_t, D_, V_, (long long)D_ * V_, (long long)D_ * V_);
  concat_bias3<<<L_, 1024, 0, stream>>>(bq, bk, bv, bqkv);

  embed_kernel<<<M_, 256, 0, stream>>>(x, emb, h32, h16);

  for (int i = 0; i < L_; i++) {
    const short* wqkv_l = wqkv_t + (long long)i * qkv_zs;
    const short* w1_l = w1_t + (long long)i * DFF_ * D_;
    const short* w2_l = w2_t + (long long)i * D_ * DFF_;

    // QKV (8-phase 2ph/K-tile, 256 blocks); V slice written transposed -> vt
    gemm8pA2<false, true><<<dim3(M_ / 256, 2048 / 128), 512, 0, stream>>>(
        h16, D_, wqkv_l, D_, qkv, 2048, vt, bqkv + (long long)i * 2048, D_);
    // scores[b] = Q[b] @ K[b]^T  f32, causal tile-skip, z-flip balanced
    gemm_bt<64, 0, false, 1, 0, true><<<dim3(S_ / 128, S_ / 64, B_), 256, 0, stream>>>(
        qkv, 2048, (long long)S_ * 2048, qkv + DA_, 2048, (long long)S_ * 2048,
        sc, S_, (long long)S_ * S_, nullptr, nullptr, S_, S_, DA_);
    // causal softmax -> P bf16 (zeros up to diagonal tile edge)
    softmax_kernel<<<dim3(S_, B_), 256, 0, stream>>>(sc, Pm);
    // att[b] = P[b] @ V[b]  f32, k-loop clipped, z-flip balanced
    gemm_bt<64, 0, false, 2, 0, true><<<dim3(S_ / 128, D_ / 64, B_), 256, 0, stream>>>(
        Pm, S_, (long long)S_ * S_, vt, M_, (long long)S_, att32, D_,
        (long long)S_ * D_, nullptr, nullptr, S_, D_, S_);
    // h16 = LN(h + att)  (h32 store elided: dead in this network)
    ln_kernel<<<M_, 256, 0, stream>>>(h32, h16, att32, ln_g + (long long)i * D_,
                                      ln_b + (long long)i * D_);
    // mid = relu(h @ W1 + b1)  bf16  (8-phase 2ph/K-tile, 256 blocks)
    gemm8pA2<true, false><<<dim3(M_ / 256, DFF_ / 128), 512, 0, stream>>>(
        h16, D_, w1_l, D_, mid, DFF_, nullptr, b1 + (long long)i * DFF_, D_);
    // h = mid @ W2 + b2 -> f32 master + bf16 shadow  (2-phase dbuf, 512 blocks)
    gemm_bt<64, 3, false, 0, 0, false><<<dim3(M_ / 128, D_ / 64, 1), 256, 0, stream>>>(
        mid, DFF_, 0, w2_l, DFF_, 0, h32, D_, 0, h16,
        b2 + (long long)i * D_, M_, D_, DFF_);
  }

  // logits = h @ Wout + bout  f32 -> d_out  (256^2 8-phase, 2000 blocks)
  gemm8p<<<dim3(M_ / 256, V_ / 256), 512, 0, stream>>>(
      h16, D_, wout_t, D_, out, V_, bout, D_);
}

// Round 14
// 2470.383 us; speedup vs baseline: 1.1165x; 1.0070x over previous
//
#include <hip/hip_runtime.h>
#include <stdint.h>

#define B_   2
#define S_   2048
#define D_   1024
#define DA_  512
#define DFF_ 2048
#define V_   32000
#define L_   12
#define M_   (B_ * S_)  // 4096

typedef __attribute__((ext_vector_type(4))) float f32x4;
typedef __attribute__((ext_vector_type(8))) short short8;
typedef __attribute__((ext_vector_type(4))) short short4v;

__device__ __forceinline__ short f2bf(float f) {
  uint32_t u = __float_as_uint(f);
  u += 0x7fffu + ((u >> 16) & 1u);
  return (short)(u >> 16);
}

__device__ __forceinline__ void gload16(const short* g, short* l) {
  __builtin_amdgcn_global_load_lds(
      (const __attribute__((address_space(1))) char*)g,
      (__attribute__((address_space(3))) char*)l, 16, 0, 0);
}

// ---------------------------------------------------------------------------
// 256x256 8-phase bf16 GEMM (T2 swizzle + T3/T4 counted vmcnt + T5 setprio).
// ---------------------------------------------------------------------------
__global__ __launch_bounds__(512, 2) void gemm8p(
    const short* __restrict__ A, int lda,
    const short* __restrict__ Bt, int ldb,
    float* __restrict__ C, int ldc,
    const float* __restrict__ bias, int K) {
  __shared__ __align__(16) short lds[2][2][256 * 64];  // [buf][A=0/B=1][row*64+c]
  const int t = threadIdx.x;
  const int lane = t & 63, wid = t >> 6;
  const int wm = wid >> 2, wn = wid & 3;
  const int l15 = lane & 15, l4 = lane >> 4;
  const int brow = blockIdx.x * 256, bcol = blockIdx.y * 256;
  const short* Ab = A + (long long)brow * lda;
  const short* Bb = Bt + (long long)bcol * ldb;

  const int rr = t >> 3;                      // row within 64-row issue block
  const int gcol = ((t & 7) ^ (rr & 7)) * 8;  // swizzled source col (elements)
  const int ldsoff = wid * 512;               // shorts: wid*8 rows * 64

  const int ord_m[8] = {0, 0, 1, 1, 1, 1, 0, 0};
  const int ord_r[8] = {0, 128, 0, 64, 128, 192, 64, 192};

#define STAGE8(mat, row0, buf, ko)                                            \
  gload16(((mat) ? Bb : Ab) +                                                 \
              (long long)((row0) + rr) * ((mat) ? ldb : lda) + (ko) + gcol,   \
          &lds[buf][mat][(row0) * 64 + ldsoff])

  f32x4 acc[8][4] = {};
  const int nkt = K >> 6;  // assumed EVEN (epilogue LDS-reuse relies on it)

  // prologue: stage tile 0 into buf 0
#pragma unroll
  for (int j = 0; j < 8; ++j) STAGE8(ord_m[j], ord_r[j], 0, 0);
  asm volatile("s_waitcnt vmcnt(2)" ::: "memory");
  __builtin_amdgcn_s_barrier();

  for (int kt = 0; kt < nkt; ++kt) {
    const int buf = kt & 1, nbuf = buf ^ 1;
    const int kon = (kt + 1 < nkt ? (kt + 1) : kt) << 6;  // clamp: uniform counts
    short8 bfr[4][2];
#pragma unroll
    for (int p = 0; p < 4; ++p) {
      short8 af[2][2];
      const int arow = wm * 128 + p * 32;
#pragma unroll
      for (int mf = 0; mf < 2; ++mf)
#pragma unroll
        for (int ks = 0; ks < 2; ++ks) {
          const int row = arow + mf * 16 + l15;
          const int cs = (ks * 32 + l4 * 8) ^ ((row & 7) << 3);
          af[mf][ks] = *(const short8*)&lds[buf][0][row * 64 + cs];
        }
      if (p == 0) {
#pragma unroll
        for (int nf = 0; nf < 4; ++nf)
#pragma unroll
          for (int ks = 0; ks < 2; ++ks) {
            const int row = wn * 64 + nf * 16 + l15;
            const int cs = (ks * 32 + l4 * 8) ^ ((row & 7) << 3);
            bfr[nf][ks] = *(const short8*)&lds[buf][1][row * 64 + cs];
          }
      }
      STAGE8(ord_m[2 * p], ord_r[2 * p], nbuf, kon);
      STAGE8(ord_m[2 * p + 1], ord_r[2 * p + 1], nbuf, kon);
      __builtin_amdgcn_s_barrier();
      asm volatile("s_waitcnt lgkmcnt(0)" ::: "memory");
      __builtin_amdgcn_sched_barrier(0);
      __builtin_amdgcn_s_setprio(1);
#pragma unroll
      for (int mf = 0; mf < 2; ++mf)
#pragma unroll
        for (int nf = 0; nf < 4; ++nf) {
          acc[p * 2 + mf][nf] = __builtin_amdgcn_mfma_f32_16x16x32_bf16(
              af[mf][0], bfr[nf][0], acc[p * 2 + mf][nf], 0, 0, 0);
          acc[p * 2 + mf][nf] = __builtin_amdgcn_mfma_f32_16x16x32_bf16(
              af[mf][1], bfr[nf][1], acc[p * 2 + mf][nf], 0, 0, 0);
        }
      __builtin_amdgcn_s_setprio(0);
      if (p == 1) asm volatile("s_waitcnt vmcnt(4)" ::: "memory");
      if (p == 3) asm volatile("s_waitcnt vmcnt(2)" ::: "memory");
      __builtin_amdgcn_s_barrier();
    }
  }

  // epilogue: acc -> per-wave LDS (stride-68 f32) -> 256-B nt f32x4 stores
  {
    float* ep = (float*)&lds[1][0][0] + wid * 1088;  // 4352 B per wave
    float bb[4];
#pragma unroll
    for (int nf = 0; nf < 4; ++nf) bb[nf] = bias[bcol + wn * 64 + nf * 16 + l15];
#pragma unroll
    for (int mi = 0; mi < 8; ++mi) {
#pragma unroll
      for (int nf = 0; nf < 4; ++nf) {
        const f32x4 v = acc[mi][nf];
#pragma unroll
        for (int j = 0; j < 4; ++j)
          ep[(l4 * 4 + j) * 68 + nf * 16 + l15] = v[j] + bb[nf];
      }
#pragma unroll
      for (int i = 0; i < 4; ++i) {
        const f32x4 v = *(const f32x4*)&ep[(l4 + 4 * i) * 68 + l15 * 4];
        const int row_g = brow + wm * 128 + mi * 16 + l4 + 4 * i;
        const int col_g = bcol + wn * 64 + l15 * 4;
        __builtin_nontemporal_store(v, (f32x4*)&C[(long long)row_g * ldc + col_g]);
      }
    }
  }
#undef STAGE8
}

// ---------------------------------------------------------------------------
// 256x128-tile, 2-PHASE-per-K-tile variant (16 MFMA/phase). TRV: V slice of
// QKV written transposed into Vt via per-wave LDS staging. Row-major path
// uses an LDS-staged wide-store epilogue (64-B contiguous short8 stores).
// ---------------------------------------------------------------------------
template <bool RELU, bool TRV>
__global__ __launch_bounds__(512, 2) void gemm8pA2(
    const short* __restrict__ A, int lda,
    const short* __restrict__ Bt, int ldb,
    short* __restrict__ C, int ldc,
    short* __restrict__ Vt,
    const float* __restrict__ bias, int K) {
  __shared__ __align__(16) short ldsA[2][256 * 64];  // 64 KB
  __shared__ __align__(16) short ldsB[2][128 * 64];  // 32 KB
  const int t = threadIdx.x;
  const int lane = t & 63, wid = t >> 6;
  const int wm = wid >> 2, wn = wid & 3;
  const int l15 = lane & 15, l4 = lane >> 4;
  const int brow = blockIdx.x * 256, bcol = blockIdx.y * 128;
  const short* Ab = A + (long long)brow * lda;
  const short* Bb = Bt + (long long)bcol * ldb;

  const int rr = t >> 3;
  const int gcol = ((t & 7) ^ (rr & 7)) * 8;
  const int ldsoff = wid * 512;

#define SA(row0, buf, ko) \
  gload16(Ab + (long long)((row0) + rr) * lda + (ko) + gcol, &ldsA[buf][(row0) * 64 + ldsoff])
#define SB(row0, buf, ko) \
  gload16(Bb + (long long)((row0) + rr) * ldb + (ko) + gcol, &ldsB[buf][(row0) * 64 + ldsoff])

  f32x4 acc[8][2] = {};
  const int nkt = K >> 6;  // EVEN (epilogue ldsB[1]-reuse relies on it)

  // prologue: tile 0 -> buf 0
  SA(0, 0, 0);
  SA(128, 0, 0);
  SB(0, 0, 0);
  SB(64, 0, 0);
  SA(64, 0, 0);
  SA(192, 0, 0);
  asm volatile("s_waitcnt vmcnt(2)" ::: "memory");
  __builtin_amdgcn_s_barrier();

  for (int kt = 0; kt < nkt; ++kt) {
    const int buf = kt & 1, nbuf = buf ^ 1;
    const int kon = (kt + 1 < nkt ? (kt + 1) : kt) << 6;  // clamp: uniform counts
    short8 bfr[2][2];
#pragma unroll
    for (int q = 0; q < 2; ++q) {
      short8 af[4][2];
      const int arow = wm * 128 + q * 64;
#pragma unroll
      for (int mf = 0; mf < 4; ++mf)
#pragma unroll
        for (int ks = 0; ks < 2; ++ks) {
          const int row = arow + mf * 16 + l15;
          const int cs = (ks * 32 + l4 * 8) ^ ((row & 7) << 3);
          af[mf][ks] = *(const short8*)&ldsA[buf][row * 64 + cs];
        }
      if (q == 0) {
#pragma unroll
        for (int nf = 0; nf < 2; ++nf)
#pragma unroll
          for (int ks = 0; ks < 2; ++ks) {
            const int row = wn * 32 + nf * 16 + l15;
            const int cs = (ks * 32 + l4 * 8) ^ ((row & 7) << 3);
            bfr[nf][ks] = *(const short8*)&ldsB[buf][row * 64 + cs];
          }
        SA(0, nbuf, kon);
        SA(128, nbuf, kon);
        SB(0, nbuf, kon);
      } else {
        SB(64, nbuf, kon);
        SA(64, nbuf, kon);
        SA(192, nbuf, kon);
      }
      __builtin_amdgcn_s_barrier();
      asm volatile("s_waitcnt lgkmcnt(0)" ::: "memory");
      __builtin_amdgcn_sched_barrier(0);
      __builtin_amdgcn_s_setprio(1);
#pragma unroll
      for (int mf = 0; mf < 4; ++mf)
#pragma unroll
        for (int nf = 0; nf < 2; ++nf) {
          acc[q * 4 + mf][nf] = __builtin_amdgcn_mfma_f32_16x16x32_bf16(
              af[mf][0], bfr[nf][0], acc[q * 4 + mf][nf], 0, 0, 0);
          acc[q * 4 + mf][nf] = __builtin_amdgcn_mfma_f32_16x16x32_bf16(
              af[mf][1], bfr[nf][1], acc[q * 4 + mf][nf], 0, 0, 0);
        }
      __builtin_amdgcn_s_setprio(0);
      if (q == 0) asm volatile("s_waitcnt vmcnt(3)" ::: "memory");
      else        asm volatile("s_waitcnt vmcnt(2)" ::: "memory");
      __builtin_amdgcn_s_barrier();
    }
  }

  if (TRV && bcol >= 1024) {
    // transposed epilogue -> Vt[vcol][M]
    __shared__ __align__(16) short eplds[8][2176];  // 16 cols x 136 stride
    short* ep = eplds[wid];
    const int vc0 = bcol - 1024 + wn * 32;
#pragma unroll
    for (int nf = 0; nf < 2; ++nf) {
      const float bb = bias[bcol + wn * 32 + nf * 16 + l15];
#pragma unroll
      for (int mi = 0; mi < 8; ++mi) {
        short4v pk;
#pragma unroll
        for (int j = 0; j < 4; ++j) pk[j] = f2bf(acc[mi][nf][j] + bb);
        *(short4v*)&ep[l15 * 136 + mi * 16 + l4 * 4] = pk;
      }
#pragma unroll
      for (int rd = 0; rd < 4; ++rd) {
        const int cl = rd * 4 + (lane >> 4);  // col-local 0..15
        const int rc = (lane & 15) * 8;       // row chunk
        const short8 v = *(const short8*)&ep[cl * 136 + rc];
        *(short8*)(Vt + (long long)(vc0 + nf * 16 + cl) * M_ + brow + wm * 128 + rc) = v;
      }
    }
  } else {
    // LDS-staged wide-store epilogue: per-wave 16 rows x 48-short region in
    // ldsB[1] (safe: nkt even; loop ended with s_barrier). 64-B short8 stores.
    short* ep = &ldsB[1][wid * 768];  // 16*48 shorts = 1536 B per wave
    const int rr2 = lane >> 2;        // read row 0..15
    const int ch = lane & 3;          // read chunk (8 shorts)
    float bb[2];
#pragma unroll
    for (int nf = 0; nf < 2; ++nf) bb[nf] = bias[bcol + wn * 32 + nf * 16 + l15];
#pragma unroll
    for (int mi = 0; mi < 8; ++mi) {
#pragma unroll
      for (int nf = 0; nf < 2; ++nf) {
        const f32x4 v = acc[mi][nf];
#pragma unroll
        for (int j = 0; j < 4; ++j) {
          float z = v[j] + bb[nf];
          if (RELU) z = fmaxf(z, 0.0f);
          ep[(l4 * 4 + j) * 48 + nf * 16 + l15] = f2bf(z);
        }
      }
      const short8 w8 = *(const short8*)&ep[rr2 * 48 + ch * 8];
      const int row_g = brow + wm * 128 + mi * 16 + rr2;
      const int col_g = bcol + wn * 32 + ch * 8;
      *(short8*)(C + (long long)row_g * ldc + col_g) = w8;
    }
  }
#undef SA
#undef SB
}

// ---------------------------------------------------------------------------
// bf16 MFMA GEMM: C[M,N] = act(A[M,K] @ Bt[N,K]^T + bias)
// Tile: 128 x BN, BK=64. T3-minimum 2-phase dbuf, one __syncthreads/K-step.
// FLIP: reverse bm for z==1 (causal load balance). OUT_MODE 0 uses an
// LDS-staged wide-store epilogue (256-B f32x4 segments) overlaid on As
// (safe: final iter issues no prefetch; loop ends with __syncthreads).
// ---------------------------------------------------------------------------
template <int BN, int OUT_MODE, bool RELU, int CAUSAL, int BIAS_MODE, bool FLIP>
__global__ __launch_bounds__(256) void gemm_bt(
    const short* __restrict__ A, int lda, long long batchA,
    const short* __restrict__ Bt, int ldb, long long batchB,
    void* __restrict__ Cp, int ldc, long long batchC,
    void* __restrict__ Cp2, const float* __restrict__ bias, int M, int N, int K) {
  const int bz = blockIdx.z;
  const int bm = (FLIP && bz == 1) ? (gridDim.x - 1 - blockIdx.x) : blockIdx.x;
  const int bn = blockIdx.y;
  if (CAUSAL == 1 && bn * BN >= bm * 128 + 128) return;
  const int brow = bm * 128, bcol = bn * BN;
  const short* Ab = A + (long long)bz * batchA;
  const short* Bb = Bt + (long long)bz * batchB;

  const int kend = (CAUSAL == 2) ? min(K, brow + 128) : K;

  __shared__ __align__(16) short As[2][128 * 64];
  __shared__ __align__(16) short Bs[2][BN * 64];

  const int t = threadIdx.x;
  const int lane = t & 63, wid = t >> 6;
  constexpr int M_REP = (BN == 128) ? 4 : 2;
  const int wr = (BN == 128) ? (wid >> 1) : wid;
  const int wc = (BN == 128) ? (wid & 1) : 0;
  const int rbase = wr * (M_REP * 16);
  const int cbase = wc * 64;
  const int l15 = lane & 15, l4 = lane >> 4;

  f32x4 acc[M_REP][4] = {};

  auto stage = [&](int buf, int ko) {
#pragma unroll
    for (int i = 0; i < 4; i++) {
      const int c = t + i * 256;
      gload16(Ab + (long long)(brow + (c >> 3)) * lda + ko + ((c & 7) << 3),
              As[buf] + (i * 256 + wid * 64) * 8);
    }
#pragma unroll
    for (int i = 0; i < BN / 32; i++) {
      const int c = t + i * 256;
      gload16(Bb + (long long)(bcol + (c >> 3)) * ldb + ko + ((c & 7) << 3),
              Bs[buf] + (i * 256 + wid * 64) * 8);
    }
  };

  stage(0, 0);
  __syncthreads();  // drain prologue stage
  int cur = 0;
  for (int ko = 0; ko < kend; ko += 64) {
    if (ko + 64 < kend) stage(cur ^ 1, ko + 64);  // prefetch next (uniform cond)
#pragma unroll
    for (int ks = 0; ks < 2; ks++) {
      short8 af[M_REP], bfr[4];
#pragma unroll
      for (int m = 0; m < M_REP; m++)
        af[m] = *(const short8*)(As[cur] + (rbase + m * 16 + l15) * 64 + ks * 32 + l4 * 8);
#pragma unroll
      for (int n = 0; n < 4; n++)
        bfr[n] = *(const short8*)(Bs[cur] + (cbase + n * 16 + l15) * 64 + ks * 32 + l4 * 8);
#pragma unroll
      for (int m = 0; m < M_REP; m++)
#pragma unroll
        for (int n = 0; n < 4; n++)
          acc[m][n] = __builtin_amdgcn_mfma_f32_16x16x32_bf16(af[m], bfr[n], acc[m][n], 0, 0, 0);
    }
    __syncthreads();  // drains prefetch vmcnt; guards LDS reuse next iter
    cur ^= 1;
  }

  if (OUT_MODE == 0) {
    // staged wide-store: per-wave 16 rows x 68-f32 region in As (4352 B/wave,
    // 4 waves = 17.4 KB <= 32 KB). 16 lanes x 16 B = 256-B full segments.
    float* C = (float*)Cp + (long long)bz * batchC;
    float* ep = (float*)&As[0][0] + wid * 1088;
    float bb4[4];
#pragma unroll
    for (int n = 0; n < 4; n++)
      bb4[n] = bias ? bias[bcol + cbase + n * 16 + l15] : 0.0f;
#pragma unroll
    for (int m = 0; m < M_REP; m++) {
#pragma unroll
      for (int n = 0; n < 4; n++) {
        const f32x4 v = acc[m][n];
#pragma unroll
        for (int j = 0; j < 4; j++)
          ep[(l4 * 4 + j) * 68 + n * 16 + l15] = v[j] + bb4[n];
      }
#pragma unroll
      for (int i = 0; i < 4; i++) {
        const f32x4 v = *(const f32x4*)&ep[(l4 + 4 * i) * 68 + l15 * 4];
        const int row_g = brow + rbase + m * 16 + l4 + 4 * i;
        const int col_g = bcol + cbase + l15 * 4;
        *(f32x4*)&C[(long long)row_g * ldc + col_g] = v;
      }
    }
  } else {
#pragma unroll
    for (int n = 0; n < 4; n++) {
      const int col = bcol + cbase + n * 16 + l15;
      const float bcv = (BIAS_MODE == 0 && bias) ? bias[col] : 0.0f;
#pragma unroll
      for (int m = 0; m < M_REP; m++) {
        const int row0 = brow + rbase + m * 16 + l4 * 4;
        f32x4 v = acc[m][n];
#pragma unroll
        for (int j = 0; j < 4; j++) {
          const float bb = (BIAS_MODE == 0) ? bcv : (bias ? bias[row0 + j] : 0.0f);
          float z = v[j] + bb;
          if (RELU) z = fmaxf(z, 0.0f);
          v[j] = z;
        }
        if (OUT_MODE == 1) {
          short* C = (short*)Cp + (long long)bz * batchC;
#pragma unroll
          for (int j = 0; j < 4; j++) C[(long long)(row0 + j) * ldc + col] = f2bf(v[j]);
        } else {  // 3: dual f32 + bf16
          float* C = (float*)Cp;
          short* C2 = (short*)Cp2;
#pragma unroll
          for (int j = 0; j < 4; j++) {
            C[(long long)(row0 + j) * ldc + col] = v[j];
            C2[(long long)(row0 + j) * ldc + col] = f2bf(v[j]);
          }
        }
      }
    }
  }
}

// ---------------------------------------------------------------------------
// Weight prep: f32 [Z][R][C] (z-stride in_zs) -> bf16 [Z][C][R] (z-stride out_zs)
// ---------------------------------------------------------------------------
__global__ void transpose_convert(const float* __restrict__ in, short* __restrict__ out,
                                  int R, int C, long long in_zs, long long out_zs) {
  __shared__ float tile[32][33];
  in += (long long)blockIdx.z * in_zs;
  out += (long long)blockIdx.z * out_zs;
  const int c0 = blockIdx.x * 32, r0 = blockIdx.y * 32;
  const int tx = threadIdx.x, ty = threadIdx.y;
#pragma unroll
  for (int i = 0; i < 32; i += 8)
    tile[ty + i][tx] = in[(long long)(r0 + ty + i) * C + (c0 + tx)];
  __syncthreads();
#pragma unroll
  for (int i = 0; i < 32; i += 8)
    out[(long long)(c0 + ty + i) * R + (r0 + tx)] = f2bf(tile[tx][ty + i]);
}

__global__ void concat_bias3(const float* __restrict__ bq, const float* __restrict__ bk,
                             const float* __restrict__ bv, float* __restrict__ dst) {
  const int l = blockIdx.x, t = threadIdx.x;  // 1024 threads
  if (t < 512) {
    dst[(long long)l * 2048 + t] = bq[(long long)l * 512 + t];
    dst[(long long)l * 2048 + 512 + t] = bk[(long long)l * 512 + t];
  }
  dst[(long long)l * 2048 + 1024 + t] = bv[(long long)l * 1024 + t];
}

__global__ void embed_kernel(const int* __restrict__ x, const float* __restrict__ emb,
                             float* __restrict__ h32, short* __restrict__ h16) {
  const int m = blockIdx.x, t = threadIdx.x;
  const int tok = x[m];
  f32x4 v = ((const f32x4*)(emb + (long long)tok * D_))[t];
  ((f32x4*)(h32 + (long long)m * D_))[t] = v;
  short4v s;
#pragma unroll
  for (int j = 0; j < 4; j++) s[j] = f2bf(v[j]);
  ((short4v*)(h16 + (long long)m * D_))[t] = s;
}

// Wave-per-row causal softmax: the whole 2048-f32 row lives in 32 VGPRs/lane.
// 4 independent waves per block, no LDS, no barriers; exp computed once.
__global__ __launch_bounds__(256) void softmax_kernel(const float* __restrict__ scores,
                                                      short* __restrict__ P) {
  const int wid = threadIdx.x >> 6, lane = threadIdx.x & 63;
  const int r = blockIdx.x * 4 + wid, b = blockIdx.y;
  const float* srow = scores + ((long long)b * S_ + r) * S_;
  short* prow = P + ((long long)b * S_ + r) * S_;
  const int n = r + 1;                          // valid columns
  const int nw = min(S_, ((r >> 7) + 1) << 7);  // 128-aligned write extent
  f32x4 pr[8];
  float mx = -3.4e38f;
#pragma unroll
  for (int j = 0; j < 8; ++j) {
    if (j * 256 < nw) {  // wave-uniform
      const int c0 = j * 256 + lane * 4;
      pr[j] = *(const f32x4*)(srow + c0);
#pragma unroll
      for (int e = 0; e < 4; ++e)
        if (c0 + e < n) mx = fmaxf(mx, pr[j][e]);
    }
  }
  for (int off = 32; off; off >>= 1) mx = fmaxf(mx, __shfl_down(mx, off));
  mx = __shfl(mx, 0);
  float sum = 0.f;
#pragma unroll
  for (int j = 0; j < 8; ++j) {
    if (j * 256 < nw) {
      const int c0 = j * 256 + lane * 4;
#pragma unroll
      for (int e = 0; e < 4; ++e) {
        const float v = (c0 + e < n) ? __expf(pr[j][e] - mx) : 0.0f;
        pr[j][e] = v;
        sum += v;
      }
    }
  }
  for (int off = 32; off; off >>= 1) sum += __shfl_down(sum, off);
  sum = __shfl(sum, 0);
  const float inv = 1.0f / sum;
#pragma unroll
  for (int j = 0; j < 8; ++j) {
    const int c0 = j * 256 + lane * 4;
    if (c0 < nw) {  // per-lane; 4-elem group never straddles the 128 boundary
      short4v pk;
#pragma unroll
      for (int e = 0; e < 4; ++e) pk[e] = f2bf(pr[j][e] * inv);
      *(short4v*)(prow + c0) = pk;
    }
  }
}

// LN(h+att): writes bf16 shadow only (h32 result is dead in this network).
__global__ __launch_bounds__(256) void ln_kernel(const float* __restrict__ h32,
                                                 short* __restrict__ h16,
                                                 const float* __restrict__ att,
                                                 const float* __restrict__ g,
                                                 const float* __restrict__ bb) {
  const int m = blockIdx.x, t = threadIdx.x;
  f32x4 hv = ((const f32x4*)(h32 + (long long)m * D_))[t];
  f32x4 av = ((const f32x4*)(att + (long long)m * D_))[t];
  float y[4];
  float s = 0.f, ss = 0.f;
#pragma unroll
  for (int j = 0; j < 4; j++) {
    y[j] = hv[j] + av[j];
    s += y[j];
    ss += y[j] * y[j];
  }
  for (int off = 32; off; off >>= 1) {
    s += __shfl_down(s, off);
    ss += __shfl_down(ss, off);
  }
  __shared__ float red[8];
  const int lane = t & 63, wid = t >> 6;
  if (lane == 0) {
    red[wid] = s;
    red[4 + wid] = ss;
  }
  __syncthreads();
  s = red[0] + red[1] + red[2] + red[3];
  ss = red[4] + red[5] + red[6] + red[7];
  const float mu = s * (1.0f / D_);
  const float var = ss * (1.0f / D_) - mu * mu;
  const float inv = rsqrtf(var + 1e-5f);
  f32x4 gv = ((const f32x4*)g)[t];
  f32x4 bv = ((const f32x4*)bb)[t];
  short4v ob;
#pragma unroll
  for (int j = 0; j < 4; j++)
    ob[j] = f2bf((y[j] - mu) * inv * gv[j] + bv[j]);
  ((short4v*)(h16 + (long long)m * D_))[t] = ob;
}

// ---------------------------------------------------------------------------
extern "C" void kernel_launch(void* const* d_in, const int* in_sizes, int n_in,
                              void* d_out, int out_size, void* d_ws, size_t ws_size,
                              hipStream_t stream) {
  const int* x = (const int*)d_in[0];
  const float* emb = (const float*)d_in[1];
  const float* Wq = (const float*)d_in[2];
  const float* bq = (const float*)d_in[3];
  const float* Wk = (const float*)d_in[4];
  const float* bk = (const float*)d_in[5];
  const float* Wv = (const float*)d_in[6];
  const float* bv = (const float*)d_in[7];
  const float* ln_g = (const float*)d_in[8];
  const float* ln_b = (const float*)d_in[9];
  const float* W1 = (const float*)d_in[10];
  const float* b1 = (const float*)d_in[11];
  const float* W2 = (const float*)d_in[12];
  const float* b2 = (const float*)d_in[13];
  const float* Wout = (const float*)d_in[14];
  const float* bout = (const float*)d_in[15];
  float* out = (float*)d_out;

  char* p = (char*)d_ws;
  auto alloc = [&](long long bytes) -> char* {
    char* r = p;
    p += (bytes + 255) & ~255LL;
    return r;
  };
  // wqkv packed [L][2048 rows (q:0-511, k:512-1023, v:1024-2047)][D]
  short* wqkv_t = (short*)alloc((long long)L_ * 2048 * D_ * 2);
  short* w1_t = (short*)alloc((long long)L_ * DFF_ * D_ * 2);
  short* w2_t = (short*)alloc((long long)L_ * D_ * DFF_ * 2);
  short* wout_t = (short*)alloc((long long)V_ * D_ * 2);
  float* bqkv = (float*)alloc((long long)L_ * 2048 * 4);
  short* h16 = (short*)alloc((long long)M_ * D_ * 2);
  float* h32 = (float*)alloc((long long)M_ * D_ * 4);
  short* qkv = (short*)alloc((long long)M_ * 2048 * 2);  // [4096][2048] q|k|(v unused)
  short* vt = (short*)alloc((long long)D_ * M_ * 2);     // [1024][4096]
  float* sc = (float*)alloc((long long)B_ * S_ * S_ * 4);
  short* Pm = (short*)alloc((long long)B_ * S_ * S_ * 2);
  float* att32 = (float*)alloc((long long)M_ * D_ * 4);
  short* mid = (short*)alloc((long long)M_ * DFF_ * 2);

  const dim3 tb(32, 8);
  const long long qkv_zs = (long long)2048 * D_;
  transpose_convert<<<dim3(DA_ / 32, D_ / 32, L_), tb, 0, stream>>>(
      Wq, wqkv_t, D_, DA_, (long long)D_ * DA_, qkv_zs);
  transpose_convert<<<dim3(DA_ / 32, D_ / 32, L_), tb, 0, stream>>>(
      Wk, wqkv_t + (long long)DA_ * D_, D_, DA_, (long long)D_ * DA_, qkv_zs);
  transpose_convert<<<dim3(D_ / 32, D_ / 32, L_), tb, 0, stream>>>(
      Wv, wqkv_t + (long long)D_ * D_, D_, D_, (long long)D_ * D_, qkv_zs);
  transpose_convert<<<dim3(DFF_ / 32, D_ / 32, L_), tb, 0, stream>>>(
      W1, w1_t, D_, DFF_, (long long)D_ * DFF_, (long long)D_ * DFF_);
  transpose_convert<<<dim3(D_ / 32, DFF_ / 32, L_), tb, 0, stream>>>(
      W2, w2_t, DFF_, D_, (long long)DFF_ * D_, (long long)DFF_ * D_);
  transpose_convert<<<dim3(V_ / 32, D_ / 32, 1), tb, 0, stream>>>(
      Wout, wout_t, D_, V_, (long long)D_ * V_, (long long)D_ * V_);
  concat_bias3<<<L_, 1024, 0, stream>>>(bq, bk, bv, bqkv);

  embed_kernel<<<M_, 256, 0, stream>>>(x, emb, h32, h16);

  for (int i = 0; i < L_; i++) {
    const short* wqkv_l = wqkv_t + (long long)i * qkv_zs;
    const short* w1_l = w1_t + (long long)i * DFF_ * D_;
    const short* w2_l = w2_t + (long long)i * D_ * DFF_;

    // QKV (8-phase 2ph/K-tile, 256 blocks); V slice written transposed -> vt
    gemm8pA2<false, true><<<dim3(M_ / 256, 2048 / 128), 512, 0, stream>>>(
        h16, D_, wqkv_l, D_, qkv, 2048, vt, bqkv + (long long)i * 2048, D_);
    // scores[b] = Q[b] @ K[b]^T  f32, causal tile-skip, z-flip balanced
    gemm_bt<64, 0, false, 1, 0, true><<<dim3(S_ / 128, S_ / 64, B_), 256, 0, stream>>>(
        qkv, 2048, (long long)S_ * 2048, qkv + DA_, 2048, (long long)S_ * 2048,
        sc, S_, (long long)S_ * S_, nullptr, nullptr, S_, S_, DA_);
    // causal softmax -> P bf16 (wave-per-row, zeros up to diagonal tile edge)
    softmax_kernel<<<dim3(S_ / 4, B_), 256, 0, stream>>>(sc, Pm);
    // att[b] = P[b] @ V[b]  f32, k-loop clipped, z-flip balanced
    gemm_bt<64, 0, false, 2, 0, true><<<dim3(S_ / 128, D_ / 64, B_), 256, 0, stream>>>(
        Pm, S_, (long long)S_ * S_, vt, M_, (long long)S_, att32, D_,
        (long long)S_ * D_, nullptr, nullptr, S_, D_, S_);
    // h16 = LN(h + att)  (h32 store elided: dead in this network)
    ln_kernel<<<M_, 256, 0, stream>>>(h32, h16, att32, ln_g + (long long)i * D_,
                                      ln_b + (long long)i * D_);
    // mid = relu(h @ W1 + b1)  bf16  (8-phase 2ph/K-tile, 256 blocks)
    gemm8pA2<true, false><<<dim3(M_ / 256, DFF_ / 128), 512, 0, stream>>>(
        h16, D_, w1_l, D_, mid, DFF_, nullptr, b1 + (long long)i * DFF_, D_);
    // h = mid @ W2 + b2 -> f32 master + bf16 shadow  (2-phase dbuf, 512 blocks)
    gemm_bt<64, 3, false, 0, 0, false><<<dim3(M_ / 128, D_ / 64, 1), 256, 0, stream>>>(
        mid, DFF_, 0, w2_l, DFF_, 0, h32, D_, 0, h16,
        b2 + (long long)i * D_, M_, D_, DFF_);
  }

  // logits = h @ Wout + bout  f32 -> d_out  (256^2 8-phase, 2000 blocks)
  gemm8p<<<dim3(M_ / 256, V_ / 256), 512, 0, stream>>>(
      h16, D_, wout_t, D_, out, V_, bout, D_);
}